// Round 1
// baseline (1955.962 us; speedup 1.0000x reference)
//
#include <hip/hip_runtime.h>
#include <hip/hip_bf16.h>
#include <math.h>

static constexpr int NN = 100000;   // N_NODES

// ---- edge index load: dtype (int32 vs int64) decided by device-side flag ----
__device__ __forceinline__ long long ldidx(const void* __restrict__ p, long long i, int is64) {
    if (is64) return ((const long long* __restrict__)p)[i];
    return (long long)((const int* __restrict__)p)[i];
}

// Detect int64 vs int32 layout of edge_index. Values are < 2^17, so if the
// buffer is int64, every odd 32-bit word (high half) of the first 2048
// entries is zero. For int32 those words are random node ids -> nonzero.
__global__ void k_detect(const unsigned int* __restrict__ e32, int* __restrict__ flag) {
    __shared__ int any_nz;
    if (threadIdx.x == 0) any_nz = 0;
    __syncthreads();
    unsigned int nz = 0;
    for (int w = 1 + 2 * (int)threadIdx.x; w < 4096; w += 512)
        nz |= e32[w];
    if (nz) atomicOr(&any_nz, 1);
    __syncthreads();
    if (threadIdx.x == 0) *flag = (any_nz == 0) ? 1 : 0;   // 1 => int64
}

__global__ void k_initdeg(float* __restrict__ deg, int n) {
    int i = blockIdx.x * blockDim.x + threadIdx.x;
    if (i < n) deg[i] = 1.0f;   // self-loop
}

__global__ void k_deg(const void* __restrict__ eidx, const int* __restrict__ flag,
                      long long E, float* __restrict__ deg) {
    long long e = (long long)blockIdx.x * blockDim.x + threadIdx.x;
    if (e >= E) return;
    int is64 = *flag;
    long long d = ldidx(eidx, E + e, is64);   // dst row
    atomicAdd(&deg[d], 1.0f);
}

__global__ void k_rsqrt(float* __restrict__ deg, int n) {
    int i = blockIdx.x * blockDim.x + threadIdx.x;
    if (i < n) deg[i] = rsqrtf(deg[i]);
}

// H[n,M] = X[n,K] @ W[K,M]; one thread per output element.
// Wave covers consecutive o -> W row reads coalesced, x reads broadcast/L1.
template<int K, int M>
__global__ void k_gemm(const float* __restrict__ X, const float* __restrict__ W,
                       float* __restrict__ H, int n) {
    long long t = (long long)blockIdx.x * blockDim.x + threadIdx.x;
    if (t >= (long long)n * M) return;
    int i = (int)(t / M);
    int o = (int)(t % M);
    const float* __restrict__ xr = X + (long long)i * K;
    float s = 0.0f;
#pragma unroll 8
    for (int k = 0; k < K; ++k)
        s = fmaf(xr[k], W[(long long)k * M + o], s);
    H[t] = s;
}

// One thread per (edge, feature): AGG[dst,f] += H[src,f] * dinv[src]*dinv[dst]
template<int F>
__global__ void k_scatter(const void* __restrict__ eidx, const int* __restrict__ flag,
                          long long E, const float* __restrict__ dinv,
                          const float* __restrict__ H, float* __restrict__ AGG) {
    long long t = (long long)blockIdx.x * blockDim.x + threadIdx.x;
    if (t >= E * (long long)F) return;
    long long e = t / F;
    int f = (int)(t % F);
    int is64 = *flag;
    long long s = ldidx(eidx, e, is64);
    long long d = ldidx(eidx, E + e, is64);
    float norm = dinv[s] * dinv[d];
    atomicAdd(&AGG[d * F + f], H[s * F + f] * norm);
}

// Add self-loop contribution + bias, optional ReLU (in place on AGG).
template<int F, bool RELU>
__global__ void k_selfbias(const float* __restrict__ H, const float* __restrict__ dinv,
                           const float* __restrict__ b, float* __restrict__ AGG, int n) {
    long long t = (long long)blockIdx.x * blockDim.x + threadIdx.x;
    if (t >= (long long)n * F) return;
    int i = (int)(t / F);
    int f = (int)(t % F);
    float di = dinv[i];
    float v = AGG[t] + H[t] * (di * di) + b[f];
    AGG[t] = RELU ? fmaxf(v, 0.0f) : v;
}

// Layer-2 epilogue: self-loop + bias + log_softmax over 40 cols.
// One wave (64 lanes) per row; lanes 40..63 idle in value but join reductions.
__global__ void k_finish2(const float* __restrict__ H2, const float* __restrict__ dinv,
                          const float* __restrict__ b, float* __restrict__ OUT, int n) {
    long long gid = (long long)blockIdx.x * blockDim.x + threadIdx.x;
    int row = (int)(gid >> 6);
    int lane = (int)(gid & 63);
    if (row >= n) return;
    float val = 0.0f;
    float v = -INFINITY;
    if (lane < 40) {
        float di = dinv[row];
        long long idx = (long long)row * 40 + lane;
        val = OUT[idx] + H2[idx] * (di * di) + b[lane];
        v = val;
    }
    #pragma unroll
    for (int off = 32; off > 0; off >>= 1) v = fmaxf(v, __shfl_xor(v, off));
    float ex = (lane < 40) ? expf(val - v) : 0.0f;
    #pragma unroll
    for (int off = 32; off > 0; off >>= 1) ex += __shfl_xor(ex, off);
    float lse = logf(ex);
    if (lane < 40) OUT[(long long)row * 40 + lane] = val - v - lse;
}

extern "C" void kernel_launch(void* const* d_in, const int* in_sizes, int n_in,
                              void* d_out, int out_size, void* d_ws, size_t ws_size,
                              hipStream_t stream) {
    const float* x  = (const float*)d_in[0];
    const void*  ei = d_in[1];
    const float* W1 = (const float*)d_in[2];
    const float* b1 = (const float*)d_in[3];
    const float* W2 = (const float*)d_in[4];
    const float* b2 = (const float*)d_in[5];
    float* out = (float*)d_out;

    const long long E = (long long)in_sizes[1] / 2;   // 3,200,000

    // ws layout (floats):
    //   [0, NN)            : deg -> dinv
    //   [NN]               : dtype flag (int)
    //   [100352, +NN*64)   : h1, later reused as h2 (NN*40 <= NN*64)
    //   [100352+NN*64, ..) : agg1 (NN*64)
    float* ws   = (float*)d_ws;
    float* dinv = ws;
    int*   flag = (int*)(ws + NN);
    float* h1   = ws + 100352;
    float* agg1 = h1 + (long long)NN * 64;
    float* h2   = h1;   // h1 dead after k_selfbias<64>

    const int B = 256;
    auto cdiv = [](long long a, long long b) { return (int)((a + b - 1) / b); };

    // 0) dtype detection
    k_detect<<<1, 256, 0, stream>>>((const unsigned int*)ei, flag);

    // 1) degrees -> dinv
    k_initdeg<<<cdiv(NN, B), B, 0, stream>>>(dinv, NN);
    k_deg<<<cdiv(E, B), B, 0, stream>>>(ei, flag, E, dinv);
    k_rsqrt<<<cdiv(NN, B), B, 0, stream>>>(dinv, NN);

    // 2) h1 = x @ W1   [NN,256]@[256,64]
    k_gemm<256, 64><<<cdiv((long long)NN * 64, B), B, 0, stream>>>(x, W1, h1, NN);

    // 3) layer-1 aggregate
    hipMemsetAsync(agg1, 0, (size_t)NN * 64 * sizeof(float), stream);
    k_scatter<64><<<cdiv(E * 64, B), B, 0, stream>>>(ei, flag, E, dinv, h1, agg1);
    k_selfbias<64, true><<<cdiv((long long)NN * 64, B), B, 0, stream>>>(h1, dinv, b1, agg1, NN);

    // 4) h2 = agg1 @ W2   [NN,64]@[64,40]
    k_gemm<64, 40><<<cdiv((long long)NN * 40, B), B, 0, stream>>>(agg1, W2, h2, NN);

    // 5) layer-2 aggregate into d_out
    hipMemsetAsync(out, 0, (size_t)out_size * sizeof(float), stream);
    k_scatter<40><<<cdiv(E * 40, B), B, 0, stream>>>(ei, flag, E, dinv, h2, out);

    // 6) self-loop + bias + log_softmax (in place on d_out)
    k_finish2<<<cdiv((long long)NN * 64, B), B, 0, stream>>>(h2, dinv, b2, out, NN);
}

// Round 2
// 1190.936 us; speedup vs baseline: 1.6424x; 1.6424x over previous
//
#include <hip/hip_runtime.h>
#include <hip/hip_bf16.h>
#include <math.h>

static constexpr int NN = 100000;   // N_NODES

// ---- edge index load: dtype (int32 vs int64) decided by device-side flag ----
__device__ __forceinline__ long long ldidx(const void* __restrict__ p, long long i, int is64) {
    if (is64) return ((const long long* __restrict__)p)[i];
    return (long long)((const int* __restrict__)p)[i];
}

// Detect int64 vs int32 layout of edge_index (node ids < 2^17 -> int64 high words zero).
__global__ void k_detect(const unsigned int* __restrict__ e32, int* __restrict__ flag) {
    __shared__ int any_nz;
    if (threadIdx.x == 0) any_nz = 0;
    __syncthreads();
    unsigned int nz = 0;
    for (int w = 1 + 2 * (int)threadIdx.x; w < 4096; w += 512)
        nz |= e32[w];
    if (nz) atomicOr(&any_nz, 1);
    __syncthreads();
    if (threadIdx.x == 0) *flag = (any_nz == 0) ? 1 : 0;   // 1 => int64
}

// ---- CSR build: histogram -> scan -> fill ----
__global__ void k_count(const void* __restrict__ eidx, const int* __restrict__ flag,
                        long long E, int* __restrict__ cnt) {
    long long e = (long long)blockIdx.x * blockDim.x + threadIdx.x;
    if (e >= E) return;
    int is64 = *flag;
    int d = (int)ldidx(eidx, E + e, is64);
    atomicAdd(&cnt[d], 1);
}

__global__ void k_dinv(const int* __restrict__ cnt, float* __restrict__ dinv, int n) {
    int i = blockIdx.x * blockDim.x + threadIdx.x;
    if (i < n) dinv[i] = rsqrtf((float)(cnt[i] + 1));   // +1 self-loop
}

// pass 1: per-block (1024 elems) sums
__global__ void k_scan_partial(const int* __restrict__ cnt, int* __restrict__ partial, int n) {
    __shared__ int sd[256];
    int tid = threadIdx.x;
    int base = blockIdx.x * 1024 + tid * 4;
    int s = 0;
#pragma unroll
    for (int k = 0; k < 4; ++k) { int i = base + k; if (i < n) s += cnt[i]; }
    sd[tid] = s; __syncthreads();
    for (int off = 128; off > 0; off >>= 1) {
        if (tid < off) sd[tid] += sd[tid + off];
        __syncthreads();
    }
    if (tid == 0) partial[blockIdx.x] = sd[0];
}

// pass 2: exclusive scan of block sums (nb <= 128), serial by one thread
__global__ void k_scan_top(int* __restrict__ partial, int nb, int* __restrict__ rowst, int n) {
    if (threadIdx.x == 0) {
        int run = 0;
        for (int i = 0; i < nb; ++i) { int v = partial[i]; partial[i] = run; run += v; }
        rowst[n] = run;   // == E
    }
}

// pass 3: per-block exclusive scan + block offset -> rowst & cursor
__global__ void k_scan_down(const int* __restrict__ cnt, const int* __restrict__ partial,
                            int* __restrict__ rowst, int* __restrict__ cursor, int n) {
    __shared__ int sd[256];
    int tid = threadIdx.x;
    int base = blockIdx.x * 1024 + tid * 4;
    int v[4]; int s = 0;
#pragma unroll
    for (int k = 0; k < 4; ++k) { int i = base + k; v[k] = (i < n) ? cnt[i] : 0; s += v[k]; }
    sd[tid] = s; __syncthreads();
    for (int off = 1; off < 256; off <<= 1) {
        int add = (tid >= off) ? sd[tid - off] : 0;
        __syncthreads();
        sd[tid] += add;
        __syncthreads();
    }
    int run = partial[blockIdx.x] + sd[tid] - s;   // exclusive offset for this thread
#pragma unroll
    for (int k = 0; k < 4; ++k) {
        int i = base + k;
        if (i < n) { rowst[i] = run; cursor[i] = run; }
        run += v[k];
    }
}

__global__ void k_fill(const void* __restrict__ eidx, const int* __restrict__ flag,
                       long long E, int* __restrict__ cursor, int* __restrict__ csr) {
    long long e = (long long)blockIdx.x * blockDim.x + threadIdx.x;
    if (e >= E) return;
    int is64 = *flag;
    int s = (int)ldidx(eidx, e, is64);
    int d = (int)ldidx(eidx, E + e, is64);
    int pos = atomicAdd(&cursor[d], 1);
    csr[pos] = s;
}

// H[i,o] = (X[i,:] @ W[:,o]) * dinv[i]   (pre-applies the src-side norm)
template<int K, int M>
__global__ void k_gemm_scaled(const float* __restrict__ X, const float* __restrict__ W,
                              const float* __restrict__ dinv, float* __restrict__ H, int n) {
    long long t = (long long)blockIdx.x * blockDim.x + threadIdx.x;
    if (t >= (long long)n * M) return;
    int i = (int)(t / M);
    int o = (int)(t % M);
    const float* __restrict__ xr = X + (long long)i * K;
    float s = 0.0f;
#pragma unroll 8
    for (int k = 0; k < K; ++k)
        s = fmaf(xr[k], W[(long long)k * M + o], s);
    H[t] = s * dinv[i];
}

// Layer-1 aggregate: one wave per node, lane = feature (F=64 exactly).
// out[d,f] = relu( dinv[d] * ( sum_src h1s[src,f] + h1s[d,f] ) + b[f] )
__global__ void __launch_bounds__(256)
k_gather_relu(const int* __restrict__ rowst, const int* __restrict__ csr,
              const float* __restrict__ h1s, const float* __restrict__ dinv,
              const float* __restrict__ b, float* __restrict__ out, int n) {
    long long gid = (long long)blockIdx.x * blockDim.x + threadIdx.x;
    int node = (int)(gid >> 6);
    int lane = (int)(gid & 63);
    if (node >= n) return;
    int jb = rowst[node], je = rowst[node + 1];
    float acc = h1s[(long long)node * 64 + lane];   // self-loop term
    int j = jb;
    for (; j + 1 < je; j += 2) {
        int s0 = csr[j], s1 = csr[j + 1];
        acc += h1s[(long long)s0 * 64 + lane];
        acc += h1s[(long long)s1 * 64 + lane];
    }
    if (j < je) {
        int s0 = csr[j];
        acc += h1s[(long long)s0 * 64 + lane];
    }
    float v = acc * dinv[node] + b[lane];
    out[(long long)node * 64 + lane] = fmaxf(v, 0.0f);
}

// Layer-2 aggregate + bias + log_softmax, one wave per node (lanes 0..39 active).
__global__ void __launch_bounds__(256)
k_gather_lsm(const int* __restrict__ rowst, const int* __restrict__ csr,
             const float* __restrict__ h2s, const float* __restrict__ dinv,
             const float* __restrict__ b, float* __restrict__ out, int n) {
    long long gid = (long long)blockIdx.x * blockDim.x + threadIdx.x;
    int node = (int)(gid >> 6);
    int lane = (int)(gid & 63);
    if (node >= n) return;
    int jb = rowst[node], je = rowst[node + 1];
    bool act = (lane < 40);
    float acc = act ? h2s[(long long)node * 40 + lane] : 0.0f;   // self-loop term
    int j = jb;
    for (; j + 1 < je; j += 2) {
        int s0 = csr[j], s1 = csr[j + 1];
        if (act) {
            acc += h2s[(long long)s0 * 40 + lane];
            acc += h2s[(long long)s1 * 40 + lane];
        }
    }
    if (j < je) {
        int s0 = csr[j];
        if (act) acc += h2s[(long long)s0 * 40 + lane];
    }
    float val = acc * dinv[node] + (act ? b[lane] : 0.0f);
    float v = act ? val : -INFINITY;
#pragma unroll
    for (int off = 32; off > 0; off >>= 1) v = fmaxf(v, __shfl_xor(v, off));
    float ex = act ? expf(val - v) : 0.0f;
#pragma unroll
    for (int off = 32; off > 0; off >>= 1) ex += __shfl_xor(ex, off);
    float lse = logf(ex);
    if (act) out[(long long)node * 40 + lane] = val - v - lse;
}

extern "C" void kernel_launch(void* const* d_in, const int* in_sizes, int n_in,
                              void* d_out, int out_size, void* d_ws, size_t ws_size,
                              hipStream_t stream) {
    const float* x  = (const float*)d_in[0];
    const void*  ei = d_in[1];
    const float* W1 = (const float*)d_in[2];
    const float* b1 = (const float*)d_in[3];
    const float* W2 = (const float*)d_in[4];
    const float* b2 = (const float*)d_in[5];
    float* out = (float*)d_out;

    const long long E = (long long)in_sizes[1] / 2;   // 3,200,000

    // workspace carve-up (256B aligned)
    char* w = (char*)d_ws;
    auto alloc = [&](size_t bytes) -> void* {
        void* p = (void*)w;
        w += (bytes + 255) & ~(size_t)255;
        return p;
    };
    int*   cnt     = (int*)  alloc((size_t)NN * 4);
    int*   rowst   = (int*)  alloc(((size_t)NN + 1) * 4);
    int*   cursor  = (int*)  alloc((size_t)NN * 4);
    int*   partial = (int*)  alloc(128 * 4);
    int*   flag    = (int*)  alloc(4);
    float* dinv    = (float*)alloc((size_t)NN * 4);
    int*   csr     = (int*)  alloc((size_t)E * 4);
    float* h1s     = (float*)alloc((size_t)NN * 64 * 4);
    float* agg1    = (float*)alloc((size_t)NN * 64 * 4);
    float* h2s     = h1s;   // h1s dead after k_gather_relu; NN*40 <= NN*64

    const int B = 256;
    auto cdiv = [](long long a, long long b) { return (int)((a + b - 1) / b); };
    const int NB = cdiv(NN, 1024);   // scan blocks (98)

    // 0) dtype detection
    k_detect<<<1, 256, 0, stream>>>((const unsigned int*)ei, flag);

    // 1) CSR build + dinv
    hipMemsetAsync(cnt, 0, (size_t)NN * 4, stream);
    k_count<<<cdiv(E, B), B, 0, stream>>>(ei, flag, E, cnt);
    k_dinv<<<cdiv(NN, B), B, 0, stream>>>(cnt, dinv, NN);
    k_scan_partial<<<NB, 256, 0, stream>>>(cnt, partial, NN);
    k_scan_top<<<1, 64, 0, stream>>>(partial, NB, rowst, NN);
    k_scan_down<<<NB, 256, 0, stream>>>(cnt, partial, rowst, cursor, NN);
    k_fill<<<cdiv(E, B), B, 0, stream>>>(ei, flag, E, cursor, csr);

    // 2) h1s = (x @ W1) * dinv[row]
    k_gemm_scaled<256, 64><<<cdiv((long long)NN * 64, B), B, 0, stream>>>(x, W1, dinv, h1s, NN);

    // 3) layer-1 aggregate + bias + ReLU (no atomics, registers -> single write)
    k_gather_relu<<<cdiv((long long)NN * 64, B), B, 0, stream>>>(rowst, csr, h1s, dinv, b1, agg1, NN);

    // 4) h2s = (agg1 @ W2) * dinv[row]
    k_gemm_scaled<64, 40><<<cdiv((long long)NN * 40, B), B, 0, stream>>>(agg1, W2, dinv, h2s, NN);

    // 5) layer-2 aggregate + bias + log_softmax -> d_out
    k_gather_lsm<<<cdiv((long long)NN * 64, B), B, 0, stream>>>(rowst, csr, h2s, dinv, b2, out, NN);
}

// Round 3
// 811.585 us; speedup vs baseline: 2.4101x; 1.4674x over previous
//
#include <hip/hip_runtime.h>
#include <hip/hip_bf16.h>
#include <math.h>

static constexpr int NN = 100000;   // N_NODES

typedef __attribute__((ext_vector_type(8))) short short8;
typedef __attribute__((ext_vector_type(4))) float f32x4;

__device__ __forceinline__ short f2bf(float f) {
    __hip_bfloat16 h = __float2bfloat16(f);
    return __builtin_bit_cast(short, h);
}

// ---- edge index load: dtype (int32 vs int64) decided by device-side flag ----
__device__ __forceinline__ long long ldidx(const void* __restrict__ p, long long i, int is64) {
    if (is64) return ((const long long* __restrict__)p)[i];
    return (long long)((const int* __restrict__)p)[i];
}

// Detect int64 vs int32 layout of edge_index (node ids < 2^17 -> int64 high words zero).
__global__ void k_detect(const unsigned int* __restrict__ e32, int* __restrict__ flag) {
    __shared__ int any_nz;
    if (threadIdx.x == 0) any_nz = 0;
    __syncthreads();
    unsigned int nz = 0;
    for (int w = 1 + 2 * (int)threadIdx.x; w < 4096; w += 512)
        nz |= e32[w];
    if (nz) atomicOr(&any_nz, 1);
    __syncthreads();
    if (threadIdx.x == 0) *flag = (any_nz == 0) ? 1 : 0;   // 1 => int64
}

// ---- CSR build: histogram -> scan -> fill ----
__global__ void k_count(const void* __restrict__ eidx, const int* __restrict__ flag,
                        long long E, int* __restrict__ cnt) {
    long long e = (long long)blockIdx.x * blockDim.x + threadIdx.x;
    if (e >= E) return;
    int is64 = *flag;
    int d = (int)ldidx(eidx, E + e, is64);
    atomicAdd(&cnt[d], 1);
}

__global__ void k_dinv(const int* __restrict__ cnt, float* __restrict__ dinv, int n) {
    int i = blockIdx.x * blockDim.x + threadIdx.x;
    if (i < n) dinv[i] = rsqrtf((float)(cnt[i] + 1));   // +1 self-loop
}

// pass 1: per-block (1024 elems) sums
__global__ void k_scan_partial(const int* __restrict__ cnt, int* __restrict__ partial, int n) {
    __shared__ int sd[256];
    int tid = threadIdx.x;
    int base = blockIdx.x * 1024 + tid * 4;
    int s = 0;
#pragma unroll
    for (int k = 0; k < 4; ++k) { int i = base + k; if (i < n) s += cnt[i]; }
    sd[tid] = s; __syncthreads();
    for (int off = 128; off > 0; off >>= 1) {
        if (tid < off) sd[tid] += sd[tid + off];
        __syncthreads();
    }
    if (tid == 0) partial[blockIdx.x] = sd[0];
}

// pass 2: exclusive scan of block sums (nb <= 128), serial by one thread
__global__ void k_scan_top(int* __restrict__ partial, int nb, int* __restrict__ rowst, int n) {
    if (threadIdx.x == 0) {
        int run = 0;
        for (int i = 0; i < nb; ++i) { int v = partial[i]; partial[i] = run; run += v; }
        rowst[n] = run;   // == E
    }
}

// pass 3: per-block exclusive scan + block offset -> rowst & cursor
__global__ void k_scan_down(const int* __restrict__ cnt, const int* __restrict__ partial,
                            int* __restrict__ rowst, int* __restrict__ cursor, int n) {
    __shared__ int sd[256];
    int tid = threadIdx.x;
    int base = blockIdx.x * 1024 + tid * 4;
    int v[4]; int s = 0;
#pragma unroll
    for (int k = 0; k < 4; ++k) { int i = base + k; v[k] = (i < n) ? cnt[i] : 0; s += v[k]; }
    sd[tid] = s; __syncthreads();
    for (int off = 1; off < 256; off <<= 1) {
        int add = (tid >= off) ? sd[tid - off] : 0;
        __syncthreads();
        sd[tid] += add;
        __syncthreads();
    }
    int run = partial[blockIdx.x] + sd[tid] - s;   // exclusive offset for this thread
#pragma unroll
    for (int k = 0; k < 4; ++k) {
        int i = base + k;
        if (i < n) { rowst[i] = run; cursor[i] = run; }
        run += v[k];
    }
}

__global__ void k_fill(const void* __restrict__ eidx, const int* __restrict__ flag,
                       long long E, int* __restrict__ cursor, int* __restrict__ csr) {
    long long e = (long long)blockIdx.x * blockDim.x + threadIdx.x;
    if (e >= E) return;
    int is64 = *flag;
    int s = (int)ldidx(eidx, e, is64);
    int d = (int)ldidx(eidx, E + e, is64);
    int pos = atomicAdd(&cursor[d], 1);
    csr[pos] = s;
}

// ---- MFMA GEMM machinery ----
// Pack W [K][NCOLS] fp32 into bf16 B-fragment layout for mfma_f32_16x16x32_bf16:
// P[((kt*NT + nt)*64 + lane)*8 + e] = bf16( W[kt*32 + (lane>>4)*8 + e][nt*16 + (lane&15)] )
// NOTE: intra-lane k-order convention only needs to MATCH the A-side packing
// (a shared k-permutation leaves the MFMA dot product invariant).
template<int K, int NCOLS, int KT, int NT>
__global__ void k_packB(const float* __restrict__ W, short* __restrict__ P) {
    int t = blockIdx.x * blockDim.x + threadIdx.x;
    if (t >= KT * NT * 64) return;
    int kt = t / (NT * 64);
    int nt = (t / 64) % NT;
    int l  = t & 63;
    int g  = l >> 4;
#pragma unroll
    for (int e = 0; e < 8; ++e) {
        int k   = kt * 32 + g * 8 + e;
        int col = nt * 16 + (l & 15);
        float v = (col < NCOLS) ? W[k * NCOLS + col] : 0.0f;
        P[t * 8 + e] = f2bf(v);
    }
}

// H[i,:] = (X[i,:K] @ W) * dinv[i], via bf16 MFMA (fp32 accumulate).
// Block = 4 waves = 64 rows; each wave: 16 rows x NT col-tiles x KT k-steps.
template<int K, int NCOLS, int KT, int NT>
__global__ void __launch_bounds__(256)
k_mfma_gemm(const float* __restrict__ X, const short* __restrict__ packedB,
            const float* __restrict__ dinv, float* __restrict__ H, int n) {
    __shared__ alignas(16) short sW[KT * NT * 512];
    short8* dst = (short8*)sW;
    const short8* src = (const short8*)packedB;
    constexpr int TOT8 = KT * NT * 64;
    for (int i = threadIdx.x; i < TOT8; i += 256) dst[i] = src[i];
    __syncthreads();

    int wave = threadIdx.x >> 6, lane = threadIdx.x & 63;
    int g = lane >> 4;
    int arow = blockIdx.x * 64 + wave * 16 + (lane & 15);
    const float* __restrict__ xr = X + (long long)arow * K;

    f32x4 acc[NT];
#pragma unroll
    for (int nt = 0; nt < NT; ++nt) acc[nt] = (f32x4){0.f, 0.f, 0.f, 0.f};

#pragma unroll
    for (int kt = 0; kt < KT; ++kt) {
        short8 a;
        if (arow < n) {
            int k0 = kt * 32 + g * 8;
            float4 u = *(const float4*)(xr + k0);
            float4 v = *(const float4*)(xr + k0 + 4);
            a[0] = f2bf(u.x); a[1] = f2bf(u.y); a[2] = f2bf(u.z); a[3] = f2bf(u.w);
            a[4] = f2bf(v.x); a[5] = f2bf(v.y); a[6] = f2bf(v.z); a[7] = f2bf(v.w);
        } else {
            a = (short8){0, 0, 0, 0, 0, 0, 0, 0};
        }
#pragma unroll
        for (int nt = 0; nt < NT; ++nt) {
            short8 b = dst[(kt * NT + nt) * 64 + lane];
            acc[nt] = __builtin_amdgcn_mfma_f32_16x16x32_bf16(a, b, acc[nt], 0, 0, 0);
        }
    }

    // C/D layout (HW-verified): col = lane&15, row = (lane>>4)*4 + reg
    int orow_base = blockIdx.x * 64 + wave * 16 + g * 4;
#pragma unroll
    for (int r = 0; r < 4; ++r) {
        int orow = orow_base + r;
        if (orow < n) {
            float di = dinv[orow];
#pragma unroll
            for (int nt = 0; nt < NT; ++nt) {
                int col = nt * 16 + (lane & 15);
                if (col < NCOLS)
                    H[(long long)orow * NCOLS + col] = acc[nt][r] * di;
            }
        }
    }
}

// Layer-1 aggregate: one wave per node, lane = feature (F=64 exactly).
__global__ void __launch_bounds__(256)
k_gather_relu(const int* __restrict__ rowst, const int* __restrict__ csr,
              const float* __restrict__ h1s, const float* __restrict__ dinv,
              const float* __restrict__ b, float* __restrict__ out, int n) {
    long long gid = (long long)blockIdx.x * blockDim.x + threadIdx.x;
    int node = (int)(gid >> 6);
    int lane = (int)(gid & 63);
    if (node >= n) return;
    int jb = rowst[node], je = rowst[node + 1];
    float acc = h1s[(long long)node * 64 + lane];   // self-loop term
    int j = jb;
    for (; j + 1 < je; j += 2) {
        int s0 = csr[j], s1 = csr[j + 1];
        acc += h1s[(long long)s0 * 64 + lane];
        acc += h1s[(long long)s1 * 64 + lane];
    }
    if (j < je) {
        int s0 = csr[j];
        acc += h1s[(long long)s0 * 64 + lane];
    }
    float v = acc * dinv[node] + b[lane];
    out[(long long)node * 64 + lane] = fmaxf(v, 0.0f);
}

// Layer-2 aggregate + bias + log_softmax, one wave per node (lanes 0..39 active).
__global__ void __launch_bounds__(256)
k_gather_lsm(const int* __restrict__ rowst, const int* __restrict__ csr,
             const float* __restrict__ h2s, const float* __restrict__ dinv,
             const float* __restrict__ b, float* __restrict__ out, int n) {
    long long gid = (long long)blockIdx.x * blockDim.x + threadIdx.x;
    int node = (int)(gid >> 6);
    int lane = (int)(gid & 63);
    if (node >= n) return;
    int jb = rowst[node], je = rowst[node + 1];
    bool act = (lane < 40);
    float acc = act ? h2s[(long long)node * 40 + lane] : 0.0f;   // self-loop term
    int j = jb;
    for (; j + 1 < je; j += 2) {
        int s0 = csr[j], s1 = csr[j + 1];
        if (act) {
            acc += h2s[(long long)s0 * 40 + lane];
            acc += h2s[(long long)s1 * 40 + lane];
        }
    }
    if (j < je) {
        int s0 = csr[j];
        if (act) acc += h2s[(long long)s0 * 40 + lane];
    }
    float val = acc * dinv[node] + (act ? b[lane] : 0.0f);
    float v = act ? val : -INFINITY;
#pragma unroll
    for (int off = 32; off > 0; off >>= 1) v = fmaxf(v, __shfl_xor(v, off));
    float ex = act ? expf(val - v) : 0.0f;
#pragma unroll
    for (int off = 32; off > 0; off >>= 1) ex += __shfl_xor(ex, off);
    float lse = logf(ex);
    if (act) out[(long long)node * 40 + lane] = val - v - lse;
}

extern "C" void kernel_launch(void* const* d_in, const int* in_sizes, int n_in,
                              void* d_out, int out_size, void* d_ws, size_t ws_size,
                              hipStream_t stream) {
    const float* x  = (const float*)d_in[0];
    const void*  ei = d_in[1];
    const float* W1 = (const float*)d_in[2];
    const float* b1 = (const float*)d_in[3];
    const float* W2 = (const float*)d_in[4];
    const float* b2 = (const float*)d_in[5];
    float* out = (float*)d_out;

    const long long E = (long long)in_sizes[1] / 2;   // 3,200,000

    // workspace carve-up (256B aligned)
    char* w = (char*)d_ws;
    auto alloc = [&](size_t bytes) -> void* {
        void* p = (void*)w;
        w += (bytes + 255) & ~(size_t)255;
        return p;
    };
    int*   cnt     = (int*)  alloc((size_t)NN * 4);
    int*   rowst   = (int*)  alloc(((size_t)NN + 1) * 4);
    int*   cursor  = (int*)  alloc((size_t)NN * 4);
    int*   partial = (int*)  alloc(128 * 4);
    int*   flag    = (int*)  alloc(4);
    float* dinv    = (float*)alloc((size_t)NN * 4);
    short* pB1     = (short*)alloc((size_t)8 * 4 * 64 * 8 * 2);   // 32 KB
    short* pB2     = (short*)alloc((size_t)2 * 3 * 64 * 8 * 2);   // 6 KB
    int*   csr     = (int*)  alloc((size_t)E * 4);
    float* h1s     = (float*)alloc((size_t)NN * 64 * 4);
    float* agg1    = (float*)alloc((size_t)NN * 64 * 4);
    float* h2s     = h1s;   // h1s dead after k_gather_relu; NN*40 <= NN*64

    const int B = 256;
    auto cdiv = [](long long a, long long b) { return (int)((a + b - 1) / b); };
    const int NB = cdiv(NN, 1024);   // scan blocks (98)

    // 0) dtype detection + weight packing (independent of edges)
    k_detect<<<1, 256, 0, stream>>>((const unsigned int*)ei, flag);
    k_packB<256, 64, 8, 4><<<cdiv(8 * 4 * 64, B), B, 0, stream>>>(W1, pB1);
    k_packB<64, 40, 2, 3><<<cdiv(2 * 3 * 64, B), B, 0, stream>>>(W2, pB2);

    // 1) CSR build + dinv
    hipMemsetAsync(cnt, 0, (size_t)NN * 4, stream);
    k_count<<<cdiv(E, B), B, 0, stream>>>(ei, flag, E, cnt);
    k_dinv<<<cdiv(NN, B), B, 0, stream>>>(cnt, dinv, NN);
    k_scan_partial<<<NB, 256, 0, stream>>>(cnt, partial, NN);
    k_scan_top<<<1, 64, 0, stream>>>(partial, NB, rowst, NN);
    k_scan_down<<<NB, 256, 0, stream>>>(cnt, partial, rowst, cursor, NN);
    k_fill<<<cdiv(E, B), B, 0, stream>>>(ei, flag, E, cursor, csr);

    // 2) h1s = (x @ W1) * dinv[row]   via bf16 MFMA
    k_mfma_gemm<256, 64, 8, 4><<<cdiv(NN, 64), B, 0, stream>>>(x, pB1, dinv, h1s, NN);

    // 3) layer-1 aggregate + bias + ReLU
    k_gather_relu<<<cdiv((long long)NN * 64, B), B, 0, stream>>>(rowst, csr, h1s, dinv, b1, agg1, NN);

    // 4) h2s = (agg1 @ W2) * dinv[row]  via bf16 MFMA
    k_mfma_gemm<64, 40, 2, 3><<<cdiv(NN, 64), B, 0, stream>>>(agg1, pB2, dinv, h2s, NN);

    // 5) layer-2 aggregate + bias + log_softmax -> d_out
    k_gather_lsm<<<cdiv((long long)NN * 64, B), B, 0, stream>>>(rowst, csr, h2s, dinv, b2, out, NN);
}

// Round 4
// 477.019 us; speedup vs baseline: 4.1004x; 1.7014x over previous
//
#include <hip/hip_runtime.h>
#include <hip/hip_bf16.h>
#include <math.h>

static constexpr int NN    = 100000;            // N_NODES
static constexpr int BSH   = 9;                 // bucket covers 512 nodes
static constexpr int NBUCK = (NN + 511) >> 9;   // 196
static constexpr int EPB   = 8192;              // edges per block in hist/scatter

typedef __attribute__((ext_vector_type(8))) short short8;
typedef __attribute__((ext_vector_type(4))) float f32x4;

__device__ __forceinline__ short f2bf(float f) {
    __hip_bfloat16 h = __float2bfloat16(f);
    return __builtin_bit_cast(short, h);
}

// ---- edge index load: dtype (int32 vs int64) decided by device-side flag ----
__device__ __forceinline__ long long ldidx(const void* __restrict__ p, long long i, int is64) {
    if (is64) return ((const long long* __restrict__)p)[i];
    return (long long)((const int* __restrict__)p)[i];
}

// Detect int64 vs int32 layout of edge_index (node ids < 2^17 -> int64 high words zero).
__global__ void k_detect(const unsigned int* __restrict__ e32, int* __restrict__ flag) {
    __shared__ int any_nz;
    if (threadIdx.x == 0) any_nz = 0;
    __syncthreads();
    unsigned int nz = 0;
    for (int w = 1 + 2 * (int)threadIdx.x; w < 4096; w += 512)
        nz |= e32[w];
    if (nz) atomicOr(&any_nz, 1);
    __syncthreads();
    if (threadIdx.x == 0) *flag = (any_nz == 0) ? 1 : 0;   // 1 => int64
}

// ---- bucketed CSR build ----
// pass A: per-block LDS histogram over NBUCK buckets -> histM[bucket][block]
__global__ void __launch_bounds__(256)
k_hist(const void* __restrict__ eidx, const int* __restrict__ flag, long long E,
       int nblk, int* __restrict__ histM) {
    __shared__ int h[NBUCK];
    for (int i = threadIdx.x; i < NBUCK; i += 256) h[i] = 0;
    __syncthreads();
    int is64 = *flag;
    long long base = (long long)blockIdx.x * EPB;
    long long end  = base + EPB < E ? base + EPB : E;
    for (long long e = base + threadIdx.x; e < end; e += 256) {
        int d = (int)ldidx(eidx, E + e, is64);
        atomicAdd(&h[d >> BSH], 1);
    }
    __syncthreads();
    for (int b = threadIdx.x; b < NBUCK; b += 256)
        histM[(long long)b * nblk + blockIdx.x] = h[b];
}

// generic 3-kernel exclusive scan over int array of length n
__global__ void k_scan_partial(const int* __restrict__ src, int* __restrict__ partial, int n) {
    __shared__ int sd[256];
    int tid = threadIdx.x;
    int base = blockIdx.x * 1024 + tid * 4;
    int s = 0;
#pragma unroll
    for (int k = 0; k < 4; ++k) { int i = base + k; if (i < n) s += src[i]; }
    sd[tid] = s; __syncthreads();
    for (int off = 128; off > 0; off >>= 1) {
        if (tid < off) sd[tid] += sd[tid + off];
        __syncthreads();
    }
    if (tid == 0) partial[blockIdx.x] = sd[0];
}

__global__ void k_scan_top(int* __restrict__ partial, int nb) {
    if (threadIdx.x == 0) {
        int run = 0;
        for (int i = 0; i < nb; ++i) { int v = partial[i]; partial[i] = run; run += v; }
    }
}

__global__ void k_scan_down(int* __restrict__ arr, const int* __restrict__ partial, int n) {
    __shared__ int sd[256];
    int tid = threadIdx.x;
    int base = blockIdx.x * 1024 + tid * 4;
    int v[4]; int s = 0;
#pragma unroll
    for (int k = 0; k < 4; ++k) { int i = base + k; v[k] = (i < n) ? arr[i] : 0; s += v[k]; }
    sd[tid] = s; __syncthreads();
    for (int off = 1; off < 256; off <<= 1) {
        int add = (tid >= off) ? sd[tid - off] : 0;
        __syncthreads();
        sd[tid] += add;
        __syncthreads();
    }
    int run = partial[blockIdx.x] + sd[tid] - s;   // exclusive offset for this thread
#pragma unroll
    for (int k = 0; k < 4; ++k) {
        int i = base + k;
        if (i < n) arr[i] = run;
        run += v[k];
    }
}

// pass B: write (src,dst) into bucket-partitioned ebuf at exact (block,bucket) offsets
__global__ void __launch_bounds__(256)
k_scatter_edges(const void* __restrict__ eidx, const int* __restrict__ flag, long long E,
                int nblk, const int* __restrict__ histM, uint2* __restrict__ ebuf) {
    __shared__ int cur[NBUCK];
    for (int b = threadIdx.x; b < NBUCK; b += 256)
        cur[b] = histM[(long long)b * nblk + blockIdx.x];
    __syncthreads();
    int is64 = *flag;
    long long base = (long long)blockIdx.x * EPB;
    long long end  = base + EPB < E ? base + EPB : E;
    for (long long e = base + threadIdx.x; e < end; e += 256) {
        int s = (int)ldidx(eidx, e, is64);
        int d = (int)ldidx(eidx, E + e, is64);
        int pos = atomicAdd(&cur[d >> BSH], 1);
        ebuf[pos] = make_uint2((unsigned)s, (unsigned)d);
    }
}

// pass C: per bucket (512 nodes): per-node counts + starts in LDS, emit rowst,
// dinv, csr (csr writes land in a dense, L2-hot ~66KB region per bucket).
__global__ void __launch_bounds__(512)
k_bucket_csr(const uint2* __restrict__ ebuf, const int* __restrict__ histM, int nblk,
             long long E, int* __restrict__ rowst, float* __restrict__ dinv,
             int* __restrict__ csr) {
    __shared__ int cnt[512];
    __shared__ int scn[512];
    __shared__ int cursor[512];
    int b = blockIdx.x;
    int t = threadIdx.x;
    long long b0 = histM[(long long)b * nblk];
    long long b1 = (b == NBUCK - 1) ? E : histM[(long long)(b + 1) * nblk];
    cnt[t] = 0;
    __syncthreads();
    for (long long e = b0 + t; e < b1; e += 512) {
        uint2 ed = ebuf[e];
        atomicAdd(&cnt[ed.y & 511], 1);
    }
    __syncthreads();
    scn[t] = cnt[t];
    __syncthreads();
    for (int off = 1; off < 512; off <<= 1) {
        int v = (t >= off) ? scn[t - off] : 0;
        __syncthreads();
        scn[t] += v;
        __syncthreads();
    }
    int start = (int)b0 + scn[t] - cnt[t];   // exclusive
    int gnode = (b << BSH) + t;
    if (gnode < NN) {
        rowst[gnode] = start;
        dinv[gnode]  = rsqrtf((float)(cnt[t] + 1));
    }
    cursor[t] = start;
    if (t == 0 && b == NBUCK - 1) rowst[NN] = (int)E;
    __syncthreads();
    for (long long e = b0 + t; e < b1; e += 512) {
        uint2 ed = ebuf[e];
        int pos = atomicAdd(&cursor[ed.y & 511], 1);
        csr[pos] = (int)ed.x;
    }
}

// ---- MFMA GEMM machinery ----
template<int K, int NCOLS, int KT, int NT>
__global__ void k_packB(const float* __restrict__ W, short* __restrict__ P) {
    int t = blockIdx.x * blockDim.x + threadIdx.x;
    if (t >= KT * NT * 64) return;
    int kt = t / (NT * 64);
    int nt = (t / 64) % NT;
    int l  = t & 63;
    int g  = l >> 4;
#pragma unroll
    for (int e = 0; e < 8; ++e) {
        int k   = kt * 32 + g * 8 + e;
        int col = nt * 16 + (l & 15);
        float v = (col < NCOLS) ? W[k * NCOLS + col] : 0.0f;
        P[t * 8 + e] = f2bf(v);
    }
}

// H[i,:] = (X[i,:K] @ W) * dinv[i], via bf16 MFMA (fp32 accumulate).
template<int K, int NCOLS, int KT, int NT>
__global__ void __launch_bounds__(256)
k_mfma_gemm(const float* __restrict__ X, const short* __restrict__ packedB,
            const float* __restrict__ dinv, float* __restrict__ H, int n) {
    __shared__ alignas(16) short sW[KT * NT * 512];
    short8* dst = (short8*)sW;
    const short8* src = (const short8*)packedB;
    constexpr int TOT8 = KT * NT * 64;
    for (int i = threadIdx.x; i < TOT8; i += 256) dst[i] = src[i];
    __syncthreads();

    int wave = threadIdx.x >> 6, lane = threadIdx.x & 63;
    int g = lane >> 4;
    int arow = blockIdx.x * 64 + wave * 16 + (lane & 15);
    const float* __restrict__ xr = X + (long long)arow * K;

    f32x4 acc[NT];
#pragma unroll
    for (int nt = 0; nt < NT; ++nt) acc[nt] = (f32x4){0.f, 0.f, 0.f, 0.f};

#pragma unroll
    for (int kt = 0; kt < KT; ++kt) {
        short8 a;
        if (arow < n) {
            int k0 = kt * 32 + g * 8;
            float4 u = *(const float4*)(xr + k0);
            float4 v = *(const float4*)(xr + k0 + 4);
            a[0] = f2bf(u.x); a[1] = f2bf(u.y); a[2] = f2bf(u.z); a[3] = f2bf(u.w);
            a[4] = f2bf(v.x); a[5] = f2bf(v.y); a[6] = f2bf(v.z); a[7] = f2bf(v.w);
        } else {
            a = (short8){0, 0, 0, 0, 0, 0, 0, 0};
        }
#pragma unroll
        for (int nt = 0; nt < NT; ++nt) {
            short8 bfr = dst[(kt * NT + nt) * 64 + lane];
            acc[nt] = __builtin_amdgcn_mfma_f32_16x16x32_bf16(a, bfr, acc[nt], 0, 0, 0);
        }
    }

    // C/D layout (HW-verified): col = lane&15, row = (lane>>4)*4 + reg
    int orow_base = blockIdx.x * 64 + wave * 16 + g * 4;
#pragma unroll
    for (int r = 0; r < 4; ++r) {
        int orow = orow_base + r;
        if (orow < n) {
            float di = dinv[orow];
#pragma unroll
            for (int nt = 0; nt < NT; ++nt) {
                int col = nt * 16 + (lane & 15);
                if (col < NCOLS)
                    H[(long long)orow * NCOLS + col] = acc[nt][r] * di;
            }
        }
    }
}

// Layer-1 aggregate: one wave per node, lane = feature (F=64 exactly).
__global__ void __launch_bounds__(256)
k_gather_relu(const int* __restrict__ rowst, const int* __restrict__ csr,
              const float* __restrict__ h1s, const float* __restrict__ dinv,
              const float* __restrict__ b, float* __restrict__ out, int n) {
    long long gid = (long long)blockIdx.x * blockDim.x + threadIdx.x;
    int node = (int)(gid >> 6);
    int lane = (int)(gid & 63);
    if (node >= n) return;
    int jb = rowst[node], je = rowst[node + 1];
    float acc = h1s[(long long)node * 64 + lane];   // self-loop term
    int j = jb;
    for (; j + 1 < je; j += 2) {
        int s0 = csr[j], s1 = csr[j + 1];
        acc += h1s[(long long)s0 * 64 + lane];
        acc += h1s[(long long)s1 * 64 + lane];
    }
    if (j < je) {
        int s0 = csr[j];
        acc += h1s[(long long)s0 * 64 + lane];
    }
    float v = acc * dinv[node] + b[lane];
    out[(long long)node * 64 + lane] = fmaxf(v, 0.0f);
}

// Layer-2 aggregate + bias + log_softmax, one wave per node (lanes 0..39 active).
__global__ void __launch_bounds__(256)
k_gather_lsm(const int* __restrict__ rowst, const int* __restrict__ csr,
             const float* __restrict__ h2s, const float* __restrict__ dinv,
             const float* __restrict__ b, float* __restrict__ out, int n) {
    long long gid = (long long)blockIdx.x * blockDim.x + threadIdx.x;
    int node = (int)(gid >> 6);
    int lane = (int)(gid & 63);
    if (node >= n) return;
    int jb = rowst[node], je = rowst[node + 1];
    bool act = (lane < 40);
    float acc = act ? h2s[(long long)node * 40 + lane] : 0.0f;   // self-loop term
    int j = jb;
    for (; j + 1 < je; j += 2) {
        int s0 = csr[j], s1 = csr[j + 1];
        if (act) {
            acc += h2s[(long long)s0 * 40 + lane];
            acc += h2s[(long long)s1 * 40 + lane];
        }
    }
    if (j < je) {
        int s0 = csr[j];
        if (act) acc += h2s[(long long)s0 * 40 + lane];
    }
    float val = acc * dinv[node] + (act ? b[lane] : 0.0f);
    float v = act ? val : -INFINITY;
#pragma unroll
    for (int off = 32; off > 0; off >>= 1) v = fmaxf(v, __shfl_xor(v, off));
    float ex = act ? expf(val - v) : 0.0f;
#pragma unroll
    for (int off = 32; off > 0; off >>= 1) ex += __shfl_xor(ex, off);
    float lse = logf(ex);
    if (act) out[(long long)node * 40 + lane] = val - v - lse;
}

extern "C" void kernel_launch(void* const* d_in, const int* in_sizes, int n_in,
                              void* d_out, int out_size, void* d_ws, size_t ws_size,
                              hipStream_t stream) {
    const float* x  = (const float*)d_in[0];
    const void*  ei = d_in[1];
    const float* W1 = (const float*)d_in[2];
    const float* b1 = (const float*)d_in[3];
    const float* W2 = (const float*)d_in[4];
    const float* b2 = (const float*)d_in[5];
    float* out = (float*)d_out;

    const long long E = (long long)in_sizes[1] / 2;   // 3,200,000
    const int nblk  = (int)((E + EPB - 1) / EPB);     // 391
    const int nscan = NBUCK * nblk;                   // 76,636

    // workspace carve-up (256B aligned)
    char* w = (char*)d_ws;
    auto alloc = [&](size_t bytes) -> void* {
        void* p = (void*)w;
        w += (bytes + 255) & ~(size_t)255;
        return p;
    };
    int*   flag    = (int*)  alloc(4);
    int*   partial = (int*)  alloc(256 * 4);
    int*   histM   = (int*)  alloc((size_t)nscan * 4);
    int*   rowst   = (int*)  alloc(((size_t)NN + 1) * 4);
    float* dinv    = (float*)alloc((size_t)NN * 4);
    short* pB1     = (short*)alloc((size_t)8 * 4 * 64 * 8 * 2);   // 32 KB
    short* pB2     = (short*)alloc((size_t)2 * 3 * 64 * 8 * 2);   // 6 KB
    int*   csr     = (int*)  alloc((size_t)E * 4);
    uint2* ebuf    = (uint2*)alloc((size_t)E * 8);
    float* agg1    = (float*)alloc((size_t)NN * 64 * 4);
    float* h1s     = (float*)ebuf;   // ebuf dead before gemm1 writes h1s
    float* h2s     = h1s;            // h1s dead after k_gather_relu

    const int B = 256;
    auto cdiv = [](long long a, long long b) { return (int)((a + b - 1) / b); };
    const int NB2 = cdiv(nscan, 1024);   // 75

    // 0) dtype detection + weight packing
    k_detect<<<1, 256, 0, stream>>>((const unsigned int*)ei, flag);
    k_packB<256, 64, 8, 4><<<cdiv(8 * 4 * 64, B), B, 0, stream>>>(W1, pB1);
    k_packB<64, 40, 2, 3><<<cdiv(2 * 3 * 64, B), B, 0, stream>>>(W2, pB2);

    // 1) bucketed CSR build (+ dinv) — all hot atomics in LDS
    k_hist<<<nblk, B, 0, stream>>>(ei, flag, E, nblk, histM);
    k_scan_partial<<<NB2, 256, 0, stream>>>(histM, partial, nscan);
    k_scan_top<<<1, 64, 0, stream>>>(partial, NB2);
    k_scan_down<<<NB2, 256, 0, stream>>>(histM, partial, nscan);
    k_scatter_edges<<<nblk, B, 0, stream>>>(ei, flag, E, nblk, histM, ebuf);
    k_bucket_csr<<<NBUCK, 512, 0, stream>>>(ebuf, histM, nblk, E, rowst, dinv, csr);

    // 2) h1s = (x @ W1) * dinv[row]   via bf16 MFMA
    k_mfma_gemm<256, 64, 8, 4><<<cdiv(NN, 64), B, 0, stream>>>(x, pB1, dinv, h1s, NN);

    // 3) layer-1 aggregate + bias + ReLU
    k_gather_relu<<<cdiv((long long)NN * 64, B), B, 0, stream>>>(rowst, csr, h1s, dinv, b1, agg1, NN);

    // 4) h2s = (agg1 @ W2) * dinv[row]  via bf16 MFMA
    k_mfma_gemm<64, 40, 2, 3><<<cdiv(NN, 64), B, 0, stream>>>(agg1, pB2, dinv, h2s, NN);

    // 5) layer-2 aggregate + bias + log_softmax -> d_out
    k_gather_lsm<<<cdiv((long long)NN * 64, B), B, 0, stream>>>(rowst, csr, h2s, dinv, b2, out, NN);
}

// Round 5
// 310.437 us; speedup vs baseline: 6.3007x; 1.5366x over previous
//
#include <hip/hip_runtime.h>
#include <hip/hip_bf16.h>
#include <math.h>

static constexpr int NN    = 100000;            // N_NODES
static constexpr int BSH   = 9;                 // bucket covers 512 nodes
static constexpr int NBUCK = (NN + 511) >> 9;   // 196
static constexpr int EPB   = 8192;              // edges per block in hist/scatter

typedef __attribute__((ext_vector_type(8))) short short8;
typedef __attribute__((ext_vector_type(4))) float f32x4;

__device__ __forceinline__ short f2bf(float f) {
    __hip_bfloat16 h = __float2bfloat16(f);
    return __builtin_bit_cast(short, h);
}
__device__ __forceinline__ float bf2f(unsigned short u) {
    return __builtin_bit_cast(float, (unsigned)u << 16);
}

// ---- edge index load: dtype (int32 vs int64) decided by device-side flag ----
__device__ __forceinline__ long long ldidx(const void* __restrict__ p, long long i, int is64) {
    if (is64) return ((const long long* __restrict__)p)[i];
    return (long long)((const int* __restrict__)p)[i];
}

// Detect int64 vs int32 layout of edge_index (node ids < 2^17 -> int64 high words zero).
__global__ void k_detect(const unsigned int* __restrict__ e32, int* __restrict__ flag) {
    __shared__ int any_nz;
    if (threadIdx.x == 0) any_nz = 0;
    __syncthreads();
    unsigned int nz = 0;
    for (int w = 1 + 2 * (int)threadIdx.x; w < 4096; w += 512)
        nz |= e32[w];
    if (nz) atomicOr(&any_nz, 1);
    __syncthreads();
    if (threadIdx.x == 0) *flag = (any_nz == 0) ? 1 : 0;   // 1 => int64
}

// ---- bucketed CSR build ----
// pass A: per-block LDS histogram over NBUCK buckets -> histM[bucket][block]
__global__ void __launch_bounds__(256)
k_hist(const void* __restrict__ eidx, const int* __restrict__ flag, long long E,
       int nblk, int* __restrict__ histM) {
    __shared__ int h[NBUCK];
    for (int i = threadIdx.x; i < NBUCK; i += 256) h[i] = 0;
    __syncthreads();
    int is64 = *flag;
    long long base = (long long)blockIdx.x * EPB;
    long long end  = base + EPB < E ? base + EPB : E;
    for (long long e = base + threadIdx.x; e < end; e += 256) {
        int d = (int)ldidx(eidx, E + e, is64);
        atomicAdd(&h[d >> BSH], 1);
    }
    __syncthreads();
    for (int b = threadIdx.x; b < NBUCK; b += 256)
        histM[(long long)b * nblk + blockIdx.x] = h[b];
}

// generic 3-kernel exclusive scan over int array of length n
__global__ void k_scan_partial(const int* __restrict__ src, int* __restrict__ partial, int n) {
    __shared__ int sd[256];
    int tid = threadIdx.x;
    int base = blockIdx.x * 1024 + tid * 4;
    int s = 0;
#pragma unroll
    for (int k = 0; k < 4; ++k) { int i = base + k; if (i < n) s += src[i]; }
    sd[tid] = s; __syncthreads();
    for (int off = 128; off > 0; off >>= 1) {
        if (tid < off) sd[tid] += sd[tid + off];
        __syncthreads();
    }
    if (tid == 0) partial[blockIdx.x] = sd[0];
}

__global__ void k_scan_top(int* __restrict__ partial, int nb) {
    if (threadIdx.x == 0) {
        int run = 0;
        for (int i = 0; i < nb; ++i) { int v = partial[i]; partial[i] = run; run += v; }
    }
}

__global__ void k_scan_down(int* __restrict__ arr, const int* __restrict__ partial, int n) {
    __shared__ int sd[256];
    int tid = threadIdx.x;
    int base = blockIdx.x * 1024 + tid * 4;
    int v[4]; int s = 0;
#pragma unroll
    for (int k = 0; k < 4; ++k) { int i = base + k; v[k] = (i < n) ? arr[i] : 0; s += v[k]; }
    sd[tid] = s; __syncthreads();
    for (int off = 1; off < 256; off <<= 1) {
        int add = (tid >= off) ? sd[tid - off] : 0;
        __syncthreads();
        sd[tid] += add;
        __syncthreads();
    }
    int run = partial[blockIdx.x] + sd[tid] - s;   // exclusive offset for this thread
#pragma unroll
    for (int k = 0; k < 4; ++k) {
        int i = base + k;
        if (i < n) arr[i] = run;
        run += v[k];
    }
}

// pass B: write packed (src | local_dst<<17) into bucket-partitioned ebuf.
// src < 2^17, local dst (dst&511) < 2^9 -> 26 bits in one uint.
__global__ void __launch_bounds__(256)
k_scatter_edges(const void* __restrict__ eidx, const int* __restrict__ flag, long long E,
                int nblk, const int* __restrict__ histM, unsigned* __restrict__ ebuf) {
    __shared__ int cur[NBUCK];
    for (int b = threadIdx.x; b < NBUCK; b += 256)
        cur[b] = histM[(long long)b * nblk + blockIdx.x];
    __syncthreads();
    int is64 = *flag;
    long long base = (long long)blockIdx.x * EPB;
    long long end  = base + EPB < E ? base + EPB : E;
    for (long long e = base + threadIdx.x; e < end; e += 256) {
        int s = (int)ldidx(eidx, e, is64);
        int d = (int)ldidx(eidx, E + e, is64);
        int pos = atomicAdd(&cur[d >> BSH], 1);
        ebuf[pos] = (unsigned)s | ((unsigned)(d & 511) << 17);
    }
}

// pass C: per bucket (512 nodes): per-node counts + starts in LDS, emit rowst,
// dinv, csr (csr writes land in a dense, L2-hot region per bucket).
__global__ void __launch_bounds__(512)
k_bucket_csr(const unsigned* __restrict__ ebuf, const int* __restrict__ histM, int nblk,
             long long E, int* __restrict__ rowst, float* __restrict__ dinv,
             int* __restrict__ csr) {
    __shared__ int cnt[512];
    __shared__ int scn[512];
    __shared__ int cursor[512];
    int b = blockIdx.x;
    int t = threadIdx.x;
    long long b0 = histM[(long long)b * nblk];
    long long b1 = (b == NBUCK - 1) ? E : histM[(long long)(b + 1) * nblk];
    cnt[t] = 0;
    __syncthreads();
    for (long long e = b0 + t; e < b1; e += 512) {
        unsigned ed = ebuf[e];
        atomicAdd(&cnt[ed >> 17], 1);
    }
    __syncthreads();
    scn[t] = cnt[t];
    __syncthreads();
    for (int off = 1; off < 512; off <<= 1) {
        int v = (t >= off) ? scn[t - off] : 0;
        __syncthreads();
        scn[t] += v;
        __syncthreads();
    }
    int start = (int)b0 + scn[t] - cnt[t];   // exclusive
    int gnode = (b << BSH) + t;
    if (gnode < NN) {
        rowst[gnode] = start;
        dinv[gnode]  = rsqrtf((float)(cnt[t] + 1));
    }
    cursor[t] = start;
    if (t == 0 && b == NBUCK - 1) rowst[NN] = (int)E;
    __syncthreads();
    for (long long e = b0 + t; e < b1; e += 512) {
        unsigned ed = ebuf[e];
        int pos = atomicAdd(&cursor[ed >> 17], 1);
        csr[pos] = (int)(ed & 0x1FFFFu);
    }
}

// ---- MFMA GEMM machinery ----
template<int K, int NCOLS, int KT, int NT>
__global__ void k_packB(const float* __restrict__ W, short* __restrict__ P) {
    int t = blockIdx.x * blockDim.x + threadIdx.x;
    if (t >= KT * NT * 64) return;
    int kt = t / (NT * 64);
    int nt = (t / 64) % NT;
    int l  = t & 63;
    int g  = l >> 4;
#pragma unroll
    for (int e = 0; e < 8; ++e) {
        int k   = kt * 32 + g * 8 + e;
        int col = nt * 16 + (l & 15);
        float v = (col < NCOLS) ? W[k * NCOLS + col] : 0.0f;
        P[t * 8 + e] = f2bf(v);
    }
}

// H[i,:] = bf16( (X[i,:K] @ W) * dinv[i] ), fp32 accumulate.
// ABF16: X is bf16 (row-aligned to 16B); else X is fp32.
template<int K, int NCOLS, int KT, int NT, bool ABF16>
__global__ void __launch_bounds__(256)
k_mfma_gemm(const void* __restrict__ Xv, const short* __restrict__ packedB,
            const float* __restrict__ dinv, unsigned short* __restrict__ H, int n) {
    __shared__ alignas(16) short sW[KT * NT * 512];
    short8* dst = (short8*)sW;
    const short8* src = (const short8*)packedB;
    constexpr int TOT8 = KT * NT * 64;
    for (int i = threadIdx.x; i < TOT8; i += 256) dst[i] = src[i];
    __syncthreads();

    int wave = threadIdx.x >> 6, lane = threadIdx.x & 63;
    int g = lane >> 4;
    int arow = blockIdx.x * 64 + wave * 16 + (lane & 15);

    f32x4 acc[NT];
#pragma unroll
    for (int nt = 0; nt < NT; ++nt) acc[nt] = (f32x4){0.f, 0.f, 0.f, 0.f};

#pragma unroll
    for (int kt = 0; kt < KT; ++kt) {
        short8 a;
        if (arow < n) {
            int k0 = kt * 32 + g * 8;
            if (ABF16) {
                const short* xr = (const short*)Xv + (long long)arow * K;
                a = *(const short8*)(xr + k0);   // rows are 16B-aligned (K mult of 8)
            } else {
                const float* xr = (const float*)Xv + (long long)arow * K;
                float4 u = *(const float4*)(xr + k0);
                float4 v = *(const float4*)(xr + k0 + 4);
                a[0] = f2bf(u.x); a[1] = f2bf(u.y); a[2] = f2bf(u.z); a[3] = f2bf(u.w);
                a[4] = f2bf(v.x); a[5] = f2bf(v.y); a[6] = f2bf(v.z); a[7] = f2bf(v.w);
            }
        } else {
            a = (short8){0, 0, 0, 0, 0, 0, 0, 0};
        }
#pragma unroll
        for (int nt = 0; nt < NT; ++nt) {
            short8 bfr = dst[(kt * NT + nt) * 64 + lane];
            acc[nt] = __builtin_amdgcn_mfma_f32_16x16x32_bf16(a, bfr, acc[nt], 0, 0, 0);
        }
    }

    // C/D layout (HW-verified): col = lane&15, row = (lane>>4)*4 + reg
    int orow_base = blockIdx.x * 64 + wave * 16 + g * 4;
#pragma unroll
    for (int r = 0; r < 4; ++r) {
        int orow = orow_base + r;
        if (orow < n) {
            float di = dinv[orow];
#pragma unroll
            for (int nt = 0; nt < NT; ++nt) {
                int col = nt * 16 + (lane & 15);
                if (col < NCOLS)
                    H[(long long)orow * NCOLS + col] =
                        (unsigned short)f2bf(acc[nt][r] * di);
            }
        }
    }
}

// Layer-1 aggregate: one wave per node, lane = feature (F=64), bf16 in/out.
__global__ void __launch_bounds__(256)
k_gather_relu(const int* __restrict__ rowst, const int* __restrict__ csr,
              const unsigned short* __restrict__ h1s, const float* __restrict__ dinv,
              const float* __restrict__ b, unsigned short* __restrict__ out, int n) {
    long long gid = (long long)blockIdx.x * blockDim.x + threadIdx.x;
    int node = (int)(gid >> 6);
    int lane = (int)(gid & 63);
    if (node >= n) return;
    int jb = rowst[node], je = rowst[node + 1];
    float acc = bf2f(h1s[(long long)node * 64 + lane]);   // self-loop term
    int j = jb;
    for (; j + 8 <= je; j += 8) {
        int s0 = csr[j],     s1 = csr[j + 1], s2 = csr[j + 2], s3 = csr[j + 3];
        int s4 = csr[j + 4], s5 = csr[j + 5], s6 = csr[j + 6], s7 = csr[j + 7];
        float v0 = bf2f(h1s[(long long)s0 * 64 + lane]);
        float v1 = bf2f(h1s[(long long)s1 * 64 + lane]);
        float v2 = bf2f(h1s[(long long)s2 * 64 + lane]);
        float v3 = bf2f(h1s[(long long)s3 * 64 + lane]);
        float v4 = bf2f(h1s[(long long)s4 * 64 + lane]);
        float v5 = bf2f(h1s[(long long)s5 * 64 + lane]);
        float v6 = bf2f(h1s[(long long)s6 * 64 + lane]);
        float v7 = bf2f(h1s[(long long)s7 * 64 + lane]);
        acc += ((v0 + v1) + (v2 + v3)) + ((v4 + v5) + (v6 + v7));
    }
    for (; j < je; ++j)
        acc += bf2f(h1s[(long long)csr[j] * 64 + lane]);
    float v = acc * dinv[node] + b[lane];
    out[(long long)node * 64 + lane] = (unsigned short)f2bf(fmaxf(v, 0.0f));
}

// Layer-2 aggregate + bias + log_softmax, bf16 in, fp32 out (lanes 0..39 active).
__global__ void __launch_bounds__(256)
k_gather_lsm(const int* __restrict__ rowst, const int* __restrict__ csr,
             const unsigned short* __restrict__ h2s, const float* __restrict__ dinv,
             const float* __restrict__ b, float* __restrict__ out, int n) {
    long long gid = (long long)blockIdx.x * blockDim.x + threadIdx.x;
    int node = (int)(gid >> 6);
    int lane = (int)(gid & 63);
    if (node >= n) return;
    int jb = rowst[node], je = rowst[node + 1];
    bool act = (lane < 40);
    int ln = act ? lane : 0;
    float acc = act ? bf2f(h2s[(long long)node * 40 + ln]) : 0.0f;   // self-loop
    int j = jb;
    for (; j + 8 <= je; j += 8) {
        int s0 = csr[j],     s1 = csr[j + 1], s2 = csr[j + 2], s3 = csr[j + 3];
        int s4 = csr[j + 4], s5 = csr[j + 5], s6 = csr[j + 6], s7 = csr[j + 7];
        if (act) {
            float v0 = bf2f(h2s[(long long)s0 * 40 + ln]);
            float v1 = bf2f(h2s[(long long)s1 * 40 + ln]);
            float v2 = bf2f(h2s[(long long)s2 * 40 + ln]);
            float v3 = bf2f(h2s[(long long)s3 * 40 + ln]);
            float v4 = bf2f(h2s[(long long)s4 * 40 + ln]);
            float v5 = bf2f(h2s[(long long)s5 * 40 + ln]);
            float v6 = bf2f(h2s[(long long)s6 * 40 + ln]);
            float v7 = bf2f(h2s[(long long)s7 * 40 + ln]);
            acc += ((v0 + v1) + (v2 + v3)) + ((v4 + v5) + (v6 + v7));
        }
    }
    for (; j < je; ++j) {
        int s0 = csr[j];
        if (act) acc += bf2f(h2s[(long long)s0 * 40 + ln]);
    }
    float val = acc * dinv[node] + (act ? b[ln] : 0.0f);
    float v = act ? val : -INFINITY;
#pragma unroll
    for (int off = 32; off > 0; off >>= 1) v = fmaxf(v, __shfl_xor(v, off));
    float ex = act ? expf(val - v) : 0.0f;
#pragma unroll
    for (int off = 32; off > 0; off >>= 1) ex += __shfl_xor(ex, off);
    float lse = logf(ex);
    if (act) out[(long long)node * 40 + lane] = val - v - lse;
}

extern "C" void kernel_launch(void* const* d_in, const int* in_sizes, int n_in,
                              void* d_out, int out_size, void* d_ws, size_t ws_size,
                              hipStream_t stream) {
    const float* x  = (const float*)d_in[0];
    const void*  ei = d_in[1];
    const float* W1 = (const float*)d_in[2];
    const float* b1 = (const float*)d_in[3];
    const float* W2 = (const float*)d_in[4];
    const float* b2 = (const float*)d_in[5];
    float* out = (float*)d_out;

    const long long E = (long long)in_sizes[1] / 2;   // 3,200,000
    const int nblk  = (int)((E + EPB - 1) / EPB);     // 391
    const int nscan = NBUCK * nblk;                   // 76,636

    // workspace carve-up (256B aligned)
    char* w = (char*)d_ws;
    auto alloc = [&](size_t bytes) -> void* {
        void* p = (void*)w;
        w += (bytes + 255) & ~(size_t)255;
        return p;
    };
    int*      flag    = (int*)     alloc(4);
    int*      partial = (int*)     alloc(256 * 4);
    int*      histM   = (int*)     alloc((size_t)nscan * 4);
    int*      rowst   = (int*)     alloc(((size_t)NN + 1) * 4);
    float*    dinv    = (float*)   alloc((size_t)NN * 4);
    short*    pB1     = (short*)   alloc((size_t)8 * 4 * 64 * 8 * 2);   // 32 KB
    short*    pB2     = (short*)   alloc((size_t)2 * 3 * 64 * 8 * 2);   // 6 KB
    int*      csr     = (int*)     alloc((size_t)E * 4);
    unsigned* ebuf    = (unsigned*)alloc((size_t)E * 4 < (size_t)NN * 64 * 2
                                         ? (size_t)NN * 64 * 2 : (size_t)E * 4);
    unsigned short* agg1 = (unsigned short*)alloc((size_t)NN * 64 * 2);
    unsigned short* h1s  = (unsigned short*)ebuf;   // ebuf dead before gemm1 writes h1s
    unsigned short* h2s  = h1s;                     // h1s dead after k_gather_relu

    const int B = 256;
    auto cdiv = [](long long a, long long b) { return (int)((a + b - 1) / b); };
    const int NB2 = cdiv(nscan, 1024);   // 75

    // 0) dtype detection + weight packing
    k_detect<<<1, 256, 0, stream>>>((const unsigned int*)ei, flag);
    k_packB<256, 64, 8, 4><<<cdiv(8 * 4 * 64, B), B, 0, stream>>>(W1, pB1);
    k_packB<64, 40, 2, 3><<<cdiv(2 * 3 * 64, B), B, 0, stream>>>(W2, pB2);

    // 1) bucketed CSR build (+ dinv) — all hot atomics in LDS
    k_hist<<<nblk, B, 0, stream>>>(ei, flag, E, nblk, histM);
    k_scan_partial<<<NB2, 256, 0, stream>>>(histM, partial, nscan);
    k_scan_top<<<1, 64, 0, stream>>>(partial, NB2);
    k_scan_down<<<NB2, 256, 0, stream>>>(histM, partial, nscan);
    k_scatter_edges<<<nblk, B, 0, stream>>>(ei, flag, E, nblk, histM, ebuf);
    k_bucket_csr<<<NBUCK, 512, 0, stream>>>(ebuf, histM, nblk, E, rowst, dinv, csr);

    // 2) h1s = bf16( (x @ W1) * dinv[row] )   via bf16 MFMA
    k_mfma_gemm<256, 64, 8, 4, false><<<cdiv(NN, 64), B, 0, stream>>>(x, pB1, dinv, h1s, NN);

    // 3) layer-1 aggregate + bias + ReLU  (bf16 -> bf16)
    k_gather_relu<<<cdiv((long long)NN * 64, B), B, 0, stream>>>(rowst, csr, h1s, dinv, b1, agg1, NN);

    // 4) h2s = bf16( (agg1 @ W2) * dinv[row] )  via bf16 MFMA, bf16 A
    k_mfma_gemm<64, 40, 2, 3, true><<<cdiv(NN, 64), B, 0, stream>>>(agg1, pB2, dinv, h2s, NN);

    // 5) layer-2 aggregate + bias + log_softmax -> d_out (fp32)
    k_gather_lsm<<<cdiv((long long)NN * 64, B), B, 0, stream>>>(rowst, csr, h2s, dinv, b2, out, NN);
}

// Round 6
// 274.933 us; speedup vs baseline: 7.1143x; 1.1291x over previous
//
#include <hip/hip_runtime.h>
#include <hip/hip_bf16.h>
#include <math.h>

static constexpr int NN    = 100000;            // N_NODES
static constexpr int BSH   = 9;                 // bucket covers 512 nodes
static constexpr int NBUCK = (NN + 511) >> 9;   // 196
static constexpr int EPB   = 8192;              // edges per block in hist/scatter

typedef __attribute__((ext_vector_type(8))) short short8;
typedef __attribute__((ext_vector_type(4))) float f32x4;

__device__ __forceinline__ short f2bf(float f) {
    __hip_bfloat16 h = __float2bfloat16(f);
    return __builtin_bit_cast(short, h);
}
__device__ __forceinline__ float bf2f(unsigned short u) {
    return __builtin_bit_cast(float, (unsigned)u << 16);
}
// unpack uint2 (4 bf16) -> add into float4 acc
__device__ __forceinline__ void acc_u2(float4& a, uint2 u) {
    a.x += bf2f((unsigned short)(u.x & 0xFFFFu));
    a.y += bf2f((unsigned short)(u.x >> 16));
    a.z += bf2f((unsigned short)(u.y & 0xFFFFu));
    a.w += bf2f((unsigned short)(u.y >> 16));
}

// ---- edge index load: dtype (int32 vs int64) decided by device-side flag ----
__device__ __forceinline__ long long ldidx(const void* __restrict__ p, long long i, int is64) {
    if (is64) return ((const long long* __restrict__)p)[i];
    return (long long)((const int* __restrict__)p)[i];
}

// Detect int64 vs int32 layout of edge_index (node ids < 2^17 -> int64 high words zero).
__global__ void k_detect(const unsigned int* __restrict__ e32, int* __restrict__ flag) {
    __shared__ int any_nz;
    if (threadIdx.x == 0) any_nz = 0;
    __syncthreads();
    unsigned int nz = 0;
    for (int w = 1 + 2 * (int)threadIdx.x; w < 4096; w += 512)
        nz |= e32[w];
    if (nz) atomicOr(&any_nz, 1);
    __syncthreads();
    if (threadIdx.x == 0) *flag = (any_nz == 0) ? 1 : 0;   // 1 => int64
}

// ---- bucketed CSR build ----
__global__ void __launch_bounds__(256)
k_hist(const void* __restrict__ eidx, const int* __restrict__ flag, long long E,
       int nblk, int* __restrict__ histM) {
    __shared__ int h[NBUCK];
    for (int i = threadIdx.x; i < NBUCK; i += 256) h[i] = 0;
    __syncthreads();
    int is64 = *flag;
    long long base = (long long)blockIdx.x * EPB;
    long long end  = base + EPB < E ? base + EPB : E;
    for (long long e = base + threadIdx.x; e < end; e += 256) {
        int d = (int)ldidx(eidx, E + e, is64);
        atomicAdd(&h[d >> BSH], 1);
    }
    __syncthreads();
    for (int b = threadIdx.x; b < NBUCK; b += 256)
        histM[(long long)b * nblk + blockIdx.x] = h[b];
}

__global__ void k_scan_partial(const int* __restrict__ src, int* __restrict__ partial, int n) {
    __shared__ int sd[256];
    int tid = threadIdx.x;
    int base = blockIdx.x * 1024 + tid * 4;
    int s = 0;
#pragma unroll
    for (int k = 0; k < 4; ++k) { int i = base + k; if (i < n) s += src[i]; }
    sd[tid] = s; __syncthreads();
    for (int off = 128; off > 0; off >>= 1) {
        if (tid < off) sd[tid] += sd[tid + off];
        __syncthreads();
    }
    if (tid == 0) partial[blockIdx.x] = sd[0];
}

__global__ void k_scan_top(int* __restrict__ partial, int nb) {
    if (threadIdx.x == 0) {
        int run = 0;
        for (int i = 0; i < nb; ++i) { int v = partial[i]; partial[i] = run; run += v; }
    }
}

__global__ void k_scan_down(int* __restrict__ arr, const int* __restrict__ partial, int n) {
    __shared__ int sd[256];
    int tid = threadIdx.x;
    int base = blockIdx.x * 1024 + tid * 4;
    int v[4]; int s = 0;
#pragma unroll
    for (int k = 0; k < 4; ++k) { int i = base + k; v[k] = (i < n) ? arr[i] : 0; s += v[k]; }
    sd[tid] = s; __syncthreads();
    for (int off = 1; off < 256; off <<= 1) {
        int add = (tid >= off) ? sd[tid - off] : 0;
        __syncthreads();
        sd[tid] += add;
        __syncthreads();
    }
    int run = partial[blockIdx.x] + sd[tid] - s;
#pragma unroll
    for (int k = 0; k < 4; ++k) {
        int i = base + k;
        if (i < n) arr[i] = run;
        run += v[k];
    }
}

// pass B: write packed (src | local_dst<<17) into bucket-partitioned ebuf.
__global__ void __launch_bounds__(256)
k_scatter_edges(const void* __restrict__ eidx, const int* __restrict__ flag, long long E,
                int nblk, const int* __restrict__ histM, unsigned* __restrict__ ebuf) {
    __shared__ int cur[NBUCK];
    for (int b = threadIdx.x; b < NBUCK; b += 256)
        cur[b] = histM[(long long)b * nblk + blockIdx.x];
    __syncthreads();
    int is64 = *flag;
    long long base = (long long)blockIdx.x * EPB;
    long long end  = base + EPB < E ? base + EPB : E;
    for (long long e = base + threadIdx.x; e < end; e += 256) {
        int s = (int)ldidx(eidx, e, is64);
        int d = (int)ldidx(eidx, E + e, is64);
        int pos = atomicAdd(&cur[d >> BSH], 1);
        ebuf[pos] = (unsigned)s | ((unsigned)(d & 511) << 17);
    }
}

// pass C: per bucket (512 nodes): counts + starts in LDS -> rowst, dinv, csr.
__global__ void __launch_bounds__(512)
k_bucket_csr(const unsigned* __restrict__ ebuf, const int* __restrict__ histM, int nblk,
             long long E, int* __restrict__ rowst, float* __restrict__ dinv,
             int* __restrict__ csr) {
    __shared__ int cnt[512];
    __shared__ int scn[512];
    __shared__ int cursor[512];
    int b = blockIdx.x;
    int t = threadIdx.x;
    long long b0 = histM[(long long)b * nblk];
    long long b1 = (b == NBUCK - 1) ? E : histM[(long long)(b + 1) * nblk];
    cnt[t] = 0;
    __syncthreads();
    for (long long e = b0 + t; e < b1; e += 512) {
        unsigned ed = ebuf[e];
        atomicAdd(&cnt[ed >> 17], 1);
    }
    __syncthreads();
    scn[t] = cnt[t];
    __syncthreads();
    for (int off = 1; off < 512; off <<= 1) {
        int v = (t >= off) ? scn[t - off] : 0;
        __syncthreads();
        scn[t] += v;
        __syncthreads();
    }
    int start = (int)b0 + scn[t] - cnt[t];
    int gnode = (b << BSH) + t;
    if (gnode < NN) {
        rowst[gnode] = start;
        dinv[gnode]  = rsqrtf((float)(cnt[t] + 1));
    }
    cursor[t] = start;
    if (t == 0 && b == NBUCK - 1) rowst[NN] = (int)E;
    __syncthreads();
    for (long long e = b0 + t; e < b1; e += 512) {
        unsigned ed = ebuf[e];
        int pos = atomicAdd(&cursor[ed >> 17], 1);
        csr[pos] = (int)(ed & 0x1FFFFu);
    }
}

// ---- MFMA GEMM machinery ----
template<int K, int NCOLS, int KT, int NT>
__global__ void k_packB(const float* __restrict__ W, short* __restrict__ P) {
    int t = blockIdx.x * blockDim.x + threadIdx.x;
    if (t >= KT * NT * 64) return;
    int kt = t / (NT * 64);
    int nt = (t / 64) % NT;
    int l  = t & 63;
    int g  = l >> 4;
#pragma unroll
    for (int e = 0; e < 8; ++e) {
        int k   = kt * 32 + g * 8 + e;
        int col = nt * 16 + (l & 15);
        float v = (col < NCOLS) ? W[k * NCOLS + col] : 0.0f;
        P[t * 8 + e] = f2bf(v);
    }
}

// H[i,:] = bf16( (X[i,:K] @ W) * dinv[i] ), fp32 accumulate.
template<int K, int NCOLS, int KT, int NT, bool ABF16>
__global__ void __launch_bounds__(256)
k_mfma_gemm(const void* __restrict__ Xv, const short* __restrict__ packedB,
            const float* __restrict__ dinv, unsigned short* __restrict__ H, int n) {
    __shared__ alignas(16) short sW[KT * NT * 512];
    short8* dst = (short8*)sW;
    const short8* src = (const short8*)packedB;
    constexpr int TOT8 = KT * NT * 64;
    for (int i = threadIdx.x; i < TOT8; i += 256) dst[i] = src[i];
    __syncthreads();

    int wave = threadIdx.x >> 6, lane = threadIdx.x & 63;
    int g = lane >> 4;
    int arow = blockIdx.x * 64 + wave * 16 + (lane & 15);

    f32x4 acc[NT];
#pragma unroll
    for (int nt = 0; nt < NT; ++nt) acc[nt] = (f32x4){0.f, 0.f, 0.f, 0.f};

#pragma unroll
    for (int kt = 0; kt < KT; ++kt) {
        short8 a;
        if (arow < n) {
            int k0 = kt * 32 + g * 8;
            if (ABF16) {
                const short* xr = (const short*)Xv + (long long)arow * K;
                a = *(const short8*)(xr + k0);
            } else {
                const float* xr = (const float*)Xv + (long long)arow * K;
                float4 u = *(const float4*)(xr + k0);
                float4 v = *(const float4*)(xr + k0 + 4);
                a[0] = f2bf(u.x); a[1] = f2bf(u.y); a[2] = f2bf(u.z); a[3] = f2bf(u.w);
                a[4] = f2bf(v.x); a[5] = f2bf(v.y); a[6] = f2bf(v.z); a[7] = f2bf(v.w);
            }
        } else {
            a = (short8){0, 0, 0, 0, 0, 0, 0, 0};
        }
#pragma unroll
        for (int nt = 0; nt < NT; ++nt) {
            short8 bfr = dst[(kt * NT + nt) * 64 + lane];
            acc[nt] = __builtin_amdgcn_mfma_f32_16x16x32_bf16(a, bfr, acc[nt], 0, 0, 0);
        }
    }

    int orow_base = blockIdx.x * 64 + wave * 16 + g * 4;
#pragma unroll
    for (int r = 0; r < 4; ++r) {
        int orow = orow_base + r;
        if (orow < n) {
            float di = dinv[orow];
#pragma unroll
            for (int nt = 0; nt < NT; ++nt) {
                int col = nt * 16 + (lane & 15);
                if (col < NCOLS)
                    H[(long long)orow * NCOLS + col] =
                        (unsigned short)f2bf(acc[nt][r] * di);
            }
        }
    }
}

// Layer-1 aggregate (F=64 bf16): one wave per node; 4 edge-groups x 16 lanes;
// each lane loads uint2 = 4 features (8B). One gather instr covers 4 edges.
__global__ void __launch_bounds__(256)
k_gather_relu(const int* __restrict__ rowst, const int* __restrict__ csr,
              const unsigned short* __restrict__ h1s, const float* __restrict__ dinv,
              const float* __restrict__ b, unsigned short* __restrict__ out, int n) {
    long long gid = (long long)blockIdx.x * blockDim.x + threadIdx.x;
    int node = (int)(gid >> 6);
    int lane = (int)(gid & 63);
    if (node >= n) return;
    int eg = lane >> 4;         // edge group 0..3
    int fe = lane & 15;         // uint2 index within row (features 4fe..4fe+3)
    int jb = rowst[node], je = rowst[node + 1];

    float4 a0 = make_float4(0.f, 0.f, 0.f, 0.f);
    float4 a1 = make_float4(0.f, 0.f, 0.f, 0.f);
    int j = jb + eg;
    for (; j + 4 < je; j += 8) {
        int s0 = csr[j];
        int s1 = csr[j + 4];
        uint2 u0 = ((const uint2*)(h1s + (long long)s0 * 64))[fe];
        uint2 u1 = ((const uint2*)(h1s + (long long)s1 * 64))[fe];
        acc_u2(a0, u0);
        acc_u2(a1, u1);
    }
    if (j < je) {
        int s0 = csr[j];
        uint2 u0 = ((const uint2*)(h1s + (long long)s0 * 64))[fe];
        acc_u2(a0, u0);
    }
    a0.x += a1.x; a0.y += a1.y; a0.z += a1.z; a0.w += a1.w;

    // sum the 4 edge-groups (lanes l, l^16, l^32, l^48)
    a0.x += __shfl_xor(a0.x, 16); a0.x += __shfl_xor(a0.x, 32);
    a0.y += __shfl_xor(a0.y, 16); a0.y += __shfl_xor(a0.y, 32);
    a0.z += __shfl_xor(a0.z, 16); a0.z += __shfl_xor(a0.z, 32);
    a0.w += __shfl_xor(a0.w, 16); a0.w += __shfl_xor(a0.w, 32);

    if (eg == 0) {
        uint2 self = ((const uint2*)(h1s + (long long)node * 64))[fe];
        acc_u2(a0, self);
        float di = dinv[node];
        float4 bv = *(const float4*)(b + 4 * fe);
        float r0 = fmaxf(a0.x * di + bv.x, 0.0f);
        float r1 = fmaxf(a0.y * di + bv.y, 0.0f);
        float r2 = fmaxf(a0.z * di + bv.z, 0.0f);
        float r3 = fmaxf(a0.w * di + bv.w, 0.0f);
        uint2 pk;
        pk.x = (unsigned)(unsigned short)f2bf(r0) | ((unsigned)(unsigned short)f2bf(r1) << 16);
        pk.y = (unsigned)(unsigned short)f2bf(r2) | ((unsigned)(unsigned short)f2bf(r3) << 16);
        ((uint2*)(out + (long long)node * 64))[fe] = pk;
    }
}

// Layer-2 aggregate + bias + log_softmax (F=40 bf16 in, fp32 out).
// 4 edge-groups x 16 lanes; row = 10 uint2 (fe<10 active).
__global__ void __launch_bounds__(256)
k_gather_lsm(const int* __restrict__ rowst, const int* __restrict__ csr,
             const unsigned short* __restrict__ h2s, const float* __restrict__ dinv,
             const float* __restrict__ b, float* __restrict__ out, int n) {
    long long gid = (long long)blockIdx.x * blockDim.x + threadIdx.x;
    int node = (int)(gid >> 6);
    int lane = (int)(gid & 63);
    if (node >= n) return;
    int eg = lane >> 4;
    int fe = lane & 15;
    bool act = (fe < 10);
    int jb = rowst[node], je = rowst[node + 1];

    float4 a0 = make_float4(0.f, 0.f, 0.f, 0.f);
    float4 a1 = make_float4(0.f, 0.f, 0.f, 0.f);
    int j = jb + eg;
    for (; j + 4 < je; j += 8) {
        int s0 = csr[j];
        int s1 = csr[j + 4];
        if (act) {
            uint2 u0 = ((const uint2*)(h2s + (long long)s0 * 40))[fe];
            uint2 u1 = ((const uint2*)(h2s + (long long)s1 * 40))[fe];
            acc_u2(a0, u0);
            acc_u2(a1, u1);
        }
    }
    if (j < je && act) {
        int s0 = csr[j];
        uint2 u0 = ((const uint2*)(h2s + (long long)s0 * 40))[fe];
        acc_u2(a0, u0);
    }
    a0.x += a1.x; a0.y += a1.y; a0.z += a1.z; a0.w += a1.w;

    a0.x += __shfl_xor(a0.x, 16); a0.x += __shfl_xor(a0.x, 32);
    a0.y += __shfl_xor(a0.y, 16); a0.y += __shfl_xor(a0.y, 32);
    a0.z += __shfl_xor(a0.z, 16); a0.z += __shfl_xor(a0.z, 32);
    a0.w += __shfl_xor(a0.w, 16); a0.w += __shfl_xor(a0.w, 32);

    // all lanes with fe<10 now hold the same group-summed acc for their features
    float v0 = -INFINITY, v1 = -INFINITY, v2 = -INFINITY, v3 = -INFINITY;
    if (act) {
        uint2 self = ((const uint2*)(h2s + (long long)node * 40))[fe];
        acc_u2(a0, self);
        float di = dinv[node];
        float4 bv = *(const float4*)(b + 4 * fe);
        v0 = a0.x * di + bv.x;
        v1 = a0.y * di + bv.y;
        v2 = a0.z * di + bv.z;
        v3 = a0.w * di + bv.w;
    }
    // wave-wide max (inactive lanes contribute -inf)
    float m = fmaxf(fmaxf(v0, v1), fmaxf(v2, v3));
#pragma unroll
    for (int off = 32; off > 0; off >>= 1) m = fmaxf(m, __shfl_xor(m, off));
    // sum of exp: only eg==0 contributes (all eg groups hold identical vals)
    float ex = 0.0f;
    if (act && eg == 0)
        ex = expf(v0 - m) + expf(v1 - m) + expf(v2 - m) + expf(v3 - m);
#pragma unroll
    for (int off = 32; off > 0; off >>= 1) ex += __shfl_xor(ex, off);
    float lse = logf(ex);
    if (act && eg == 0) {
        float4 r = make_float4(v0 - m - lse, v1 - m - lse, v2 - m - lse, v3 - m - lse);
        *(float4*)(out + (long long)node * 40 + 4 * fe) = r;
    }
}

extern "C" void kernel_launch(void* const* d_in, const int* in_sizes, int n_in,
                              void* d_out, int out_size, void* d_ws, size_t ws_size,
                              hipStream_t stream) {
    const float* x  = (const float*)d_in[0];
    const void*  ei = d_in[1];
    const float* W1 = (const float*)d_in[2];
    const float* b1 = (const float*)d_in[3];
    const float* W2 = (const float*)d_in[4];
    const float* b2 = (const float*)d_in[5];
    float* out = (float*)d_out;

    const long long E = (long long)in_sizes[1] / 2;   // 3,200,000
    const int nblk  = (int)((E + EPB - 1) / EPB);     // 391
    const int nscan = NBUCK * nblk;                   // 76,636

    char* w = (char*)d_ws;
    auto alloc = [&](size_t bytes) -> void* {
        void* p = (void*)w;
        w += (bytes + 255) & ~(size_t)255;
        return p;
    };
    int*      flag    = (int*)     alloc(4);
    int*      partial = (int*)     alloc(256 * 4);
    int*      histM   = (int*)     alloc((size_t)nscan * 4);
    int*      rowst   = (int*)     alloc(((size_t)NN + 1) * 4);
    float*    dinv    = (float*)   alloc((size_t)NN * 4);
    short*    pB1     = (short*)   alloc((size_t)8 * 4 * 64 * 8 * 2);   // 32 KB
    short*    pB2     = (short*)   alloc((size_t)2 * 3 * 64 * 8 * 2);   // 6 KB
    int*      csr     = (int*)     alloc((size_t)E * 4);
    unsigned* ebuf    = (unsigned*)alloc((size_t)E * 4 < (size_t)NN * 64 * 2
                                         ? (size_t)NN * 64 * 2 : (size_t)E * 4);
    unsigned short* agg1 = (unsigned short*)alloc((size_t)NN * 64 * 2);
    unsigned short* h1s  = (unsigned short*)ebuf;   // ebuf dead before gemm1 writes h1s
    unsigned short* h2s  = h1s;                     // h1s dead after k_gather_relu

    const int B = 256;
    auto cdiv = [](long long a, long long b) { return (int)((a + b - 1) / b); };
    const int NB2 = cdiv(nscan, 1024);   // 75

    // 0) dtype detection + weight packing
    k_detect<<<1, 256, 0, stream>>>((const unsigned int*)ei, flag);
    k_packB<256, 64, 8, 4><<<cdiv(8 * 4 * 64, B), B, 0, stream>>>(W1, pB1);
    k_packB<64, 40, 2, 3><<<cdiv(2 * 3 * 64, B), B, 0, stream>>>(W2, pB2);

    // 1) bucketed CSR build (+ dinv) — all hot atomics in LDS
    k_hist<<<nblk, B, 0, stream>>>(ei, flag, E, nblk, histM);
    k_scan_partial<<<NB2, 256, 0, stream>>>(histM, partial, nscan);
    k_scan_top<<<1, 64, 0, stream>>>(partial, NB2);
    k_scan_down<<<NB2, 256, 0, stream>>>(histM, partial, nscan);
    k_scatter_edges<<<nblk, B, 0, stream>>>(ei, flag, E, nblk, histM, ebuf);
    k_bucket_csr<<<NBUCK, 512, 0, stream>>>(ebuf, histM, nblk, E, rowst, dinv, csr);

    // 2) h1s = bf16( (x @ W1) * dinv[row] )   via bf16 MFMA
    k_mfma_gemm<256, 64, 8, 4, false><<<cdiv(NN, 64), B, 0, stream>>>(x, pB1, dinv, h1s, NN);

    // 3) layer-1 aggregate + bias + ReLU  (bf16 -> bf16)
    k_gather_relu<<<cdiv((long long)NN * 64, B), B, 0, stream>>>(rowst, csr, h1s, dinv, b1, agg1, NN);

    // 4) h2s = bf16( (agg1 @ W2) * dinv[row] )  via bf16 MFMA, bf16 A
    k_mfma_gemm<64, 40, 2, 3, true><<<cdiv(NN, 64), B, 0, stream>>>(agg1, pB2, dinv, h2s, NN);

    // 5) layer-2 aggregate + bias + log_softmax -> d_out (fp32)
    k_gather_lsm<<<cdiv((long long)NN * 64, B), B, 0, stream>>>(rowst, csr, h2s, dinv, b2, out, NN);
}

// Round 7
// 264.065 us; speedup vs baseline: 7.4071x; 1.0412x over previous
//
#include <hip/hip_runtime.h>
#include <hip/hip_bf16.h>
#include <math.h>

static constexpr int NN    = 100000;            // N_NODES
static constexpr int BSH   = 9;                 // bucket covers 512 nodes
static constexpr int NBUCK = (NN + 511) >> 9;   // 196
static constexpr int EPB   = 8192;              // edges per block in hist/scatter

typedef __attribute__((ext_vector_type(8))) short short8;
typedef __attribute__((ext_vector_type(4))) float f32x4;

__device__ __forceinline__ short f2bf(float f) {
    __hip_bfloat16 h = __float2bfloat16(f);
    return __builtin_bit_cast(short, h);
}
__device__ __forceinline__ float bf2f(unsigned short u) {
    return __builtin_bit_cast(float, (unsigned)u << 16);
}

// ---- fp8 e4m3fn via bit ops (no API dependency) ----
// decode: place sign at 31, exp+mant at 26:20, rescale by 2^120 (bias 7 -> 127).
__device__ __forceinline__ float fp8_dec(unsigned b) {
    unsigned u = ((b & 0x80u) << 24) | ((b & 0x7Fu) << 20);
    return __builtin_bit_cast(float, u) * 0x1p120f;
}
// encode with RNE; saturate at 0x7E (448). Values here are << 448.
__device__ __forceinline__ unsigned fp8_enc(float f) {
    unsigned u = __builtin_bit_cast(unsigned, f * 0x1p-120f);
    unsigned s = (u >> 24) & 0x80u;
    unsigned mag = u & 0x7FFFFFFFu;
    unsigned t = mag + 0x7FFFFu + ((mag >> 20) & 1u);
    unsigned r = t >> 20;
    if (r > 0x7Eu) r = 0x7Eu;
    return s | r;
}
// accumulate 8 fp8 (uint2) into float a[8]
__device__ __forceinline__ void acc8_fp8(float* a, uint2 u) {
#pragma unroll
    for (int k = 0; k < 4; ++k) a[k]     += fp8_dec((u.x >> (8 * k)) & 0xFFu);
#pragma unroll
    for (int k = 0; k < 4; ++k) a[k + 4] += fp8_dec((u.y >> (8 * k)) & 0xFFu);
}

// ---- edge index load: dtype (int32 vs int64) decided by device-side flag ----
__device__ __forceinline__ long long ldidx(const void* __restrict__ p, long long i, int is64) {
    if (is64) return ((const long long* __restrict__)p)[i];
    return (long long)((const int* __restrict__)p)[i];
}

__global__ void k_detect(const unsigned int* __restrict__ e32, int* __restrict__ flag) {
    __shared__ int any_nz;
    if (threadIdx.x == 0) any_nz = 0;
    __syncthreads();
    unsigned int nz = 0;
    for (int w = 1 + 2 * (int)threadIdx.x; w < 4096; w += 512)
        nz |= e32[w];
    if (nz) atomicOr(&any_nz, 1);
    __syncthreads();
    if (threadIdx.x == 0) *flag = (any_nz == 0) ? 1 : 0;   // 1 => int64
}

// ---- bucketed CSR build ----
__global__ void __launch_bounds__(256)
k_hist(const void* __restrict__ eidx, const int* __restrict__ flag, long long E,
       int nblk, int* __restrict__ histM) {
    __shared__ int h[NBUCK];
    for (int i = threadIdx.x; i < NBUCK; i += 256) h[i] = 0;
    __syncthreads();
    int is64 = *flag;
    long long base = (long long)blockIdx.x * EPB;
    long long end  = base + EPB < E ? base + EPB : E;
    for (long long e = base + threadIdx.x; e < end; e += 256) {
        int d = (int)ldidx(eidx, E + e, is64);
        atomicAdd(&h[d >> BSH], 1);
    }
    __syncthreads();
    for (int b = threadIdx.x; b < NBUCK; b += 256)
        histM[(long long)b * nblk + blockIdx.x] = h[b];
}

__global__ void k_scan_partial(const int* __restrict__ src, int* __restrict__ partial, int n) {
    __shared__ int sd[256];
    int tid = threadIdx.x;
    int base = blockIdx.x * 1024 + tid * 4;
    int s = 0;
#pragma unroll
    for (int k = 0; k < 4; ++k) { int i = base + k; if (i < n) s += src[i]; }
    sd[tid] = s; __syncthreads();
    for (int off = 128; off > 0; off >>= 1) {
        if (tid < off) sd[tid] += sd[tid + off];
        __syncthreads();
    }
    if (tid == 0) partial[blockIdx.x] = sd[0];
}

__global__ void k_scan_top(int* __restrict__ partial, int nb) {
    if (threadIdx.x == 0) {
        int run = 0;
        for (int i = 0; i < nb; ++i) { int v = partial[i]; partial[i] = run; run += v; }
    }
}

__global__ void k_scan_down(int* __restrict__ arr, const int* __restrict__ partial, int n) {
    __shared__ int sd[256];
    int tid = threadIdx.x;
    int base = blockIdx.x * 1024 + tid * 4;
    int v[4]; int s = 0;
#pragma unroll
    for (int k = 0; k < 4; ++k) { int i = base + k; v[k] = (i < n) ? arr[i] : 0; s += v[k]; }
    sd[tid] = s; __syncthreads();
    for (int off = 1; off < 256; off <<= 1) {
        int add = (tid >= off) ? sd[tid - off] : 0;
        __syncthreads();
        sd[tid] += add;
        __syncthreads();
    }
    int run = partial[blockIdx.x] + sd[tid] - s;
#pragma unroll
    for (int k = 0; k < 4; ++k) {
        int i = base + k;
        if (i < n) arr[i] = run;
        run += v[k];
    }
}

__global__ void __launch_bounds__(256)
k_scatter_edges(const void* __restrict__ eidx, const int* __restrict__ flag, long long E,
                int nblk, const int* __restrict__ histM, unsigned* __restrict__ ebuf) {
    __shared__ int cur[NBUCK];
    for (int b = threadIdx.x; b < NBUCK; b += 256)
        cur[b] = histM[(long long)b * nblk + blockIdx.x];
    __syncthreads();
    int is64 = *flag;
    long long base = (long long)blockIdx.x * EPB;
    long long end  = base + EPB < E ? base + EPB : E;
    for (long long e = base + threadIdx.x; e < end; e += 256) {
        int s = (int)ldidx(eidx, e, is64);
        int d = (int)ldidx(eidx, E + e, is64);
        int pos = atomicAdd(&cur[d >> BSH], 1);
        ebuf[pos] = (unsigned)s | ((unsigned)(d & 511) << 17);
    }
}

__global__ void __launch_bounds__(512)
k_bucket_csr(const unsigned* __restrict__ ebuf, const int* __restrict__ histM, int nblk,
             long long E, int* __restrict__ rowst, float* __restrict__ dinv,
             int* __restrict__ csr) {
    __shared__ int cnt[512];
    __shared__ int scn[512];
    __shared__ int cursor[512];
    int b = blockIdx.x;
    int t = threadIdx.x;
    long long b0 = histM[(long long)b * nblk];
    long long b1 = (b == NBUCK - 1) ? E : histM[(long long)(b + 1) * nblk];
    cnt[t] = 0;
    __syncthreads();
    for (long long e = b0 + t; e < b1; e += 512) {
        unsigned ed = ebuf[e];
        atomicAdd(&cnt[ed >> 17], 1);
    }
    __syncthreads();
    scn[t] = cnt[t];
    __syncthreads();
    for (int off = 1; off < 512; off <<= 1) {
        int v = (t >= off) ? scn[t - off] : 0;
        __syncthreads();
        scn[t] += v;
        __syncthreads();
    }
    int start = (int)b0 + scn[t] - cnt[t];
    int gnode = (b << BSH) + t;
    if (gnode < NN) {
        rowst[gnode] = start;
        dinv[gnode]  = rsqrtf((float)(cnt[t] + 1));
    }
    cursor[t] = start;
    if (t == 0 && b == NBUCK - 1) rowst[NN] = (int)E;
    __syncthreads();
    for (long long e = b0 + t; e < b1; e += 512) {
        unsigned ed = ebuf[e];
        int pos = atomicAdd(&cursor[ed >> 17], 1);
        csr[pos] = (int)(ed & 0x1FFFFu);
    }
}

// ---- MFMA GEMM machinery ----
template<int K, int NCOLS, int KT, int NT>
__global__ void k_packB(const float* __restrict__ W, short* __restrict__ P) {
    int t = blockIdx.x * blockDim.x + threadIdx.x;
    if (t >= KT * NT * 64) return;
    int kt = t / (NT * 64);
    int nt = (t / 64) % NT;
    int l  = t & 63;
    int g  = l >> 4;
#pragma unroll
    for (int e = 0; e < 8; ++e) {
        int k   = kt * 32 + g * 8 + e;
        int col = nt * 16 + (l & 15);
        float v = (col < NCOLS) ? W[k * NCOLS + col] : 0.0f;
        P[t * 8 + e] = f2bf(v);
    }
}

// H[i,:] = fp8( (X[i,:K] @ W) * dinv[i] ), fp32 accumulate via bf16 MFMA.
template<int K, int NCOLS, int KT, int NT, bool ABF16>
__global__ void __launch_bounds__(256)
k_mfma_gemm(const void* __restrict__ Xv, const short* __restrict__ packedB,
            const float* __restrict__ dinv, unsigned char* __restrict__ H, int n) {
    __shared__ alignas(16) short sW[KT * NT * 512];
    short8* dst = (short8*)sW;
    const short8* src = (const short8*)packedB;
    constexpr int TOT8 = KT * NT * 64;
    for (int i = threadIdx.x; i < TOT8; i += 256) dst[i] = src[i];
    __syncthreads();

    int wave = threadIdx.x >> 6, lane = threadIdx.x & 63;
    int g = lane >> 4;
    int arow = blockIdx.x * 64 + wave * 16 + (lane & 15);

    f32x4 acc[NT];
#pragma unroll
    for (int nt = 0; nt < NT; ++nt) acc[nt] = (f32x4){0.f, 0.f, 0.f, 0.f};

#pragma unroll
    for (int kt = 0; kt < KT; ++kt) {
        short8 a;
        if (arow < n) {
            int k0 = kt * 32 + g * 8;
            if (ABF16) {
                const short* xr = (const short*)Xv + (long long)arow * K;
                a = *(const short8*)(xr + k0);
            } else {
                const float* xr = (const float*)Xv + (long long)arow * K;
                float4 u = *(const float4*)(xr + k0);
                float4 v = *(const float4*)(xr + k0 + 4);
                a[0] = f2bf(u.x); a[1] = f2bf(u.y); a[2] = f2bf(u.z); a[3] = f2bf(u.w);
                a[4] = f2bf(v.x); a[5] = f2bf(v.y); a[6] = f2bf(v.z); a[7] = f2bf(v.w);
            }
        } else {
            a = (short8){0, 0, 0, 0, 0, 0, 0, 0};
        }
#pragma unroll
        for (int nt = 0; nt < NT; ++nt) {
            short8 bfr = dst[(kt * NT + nt) * 64 + lane];
            acc[nt] = __builtin_amdgcn_mfma_f32_16x16x32_bf16(a, bfr, acc[nt], 0, 0, 0);
        }
    }

    // C/D layout (HW-verified): col = lane&15, row = (lane>>4)*4 + reg
    int orow_base = blockIdx.x * 64 + wave * 16 + g * 4;
#pragma unroll
    for (int r = 0; r < 4; ++r) {
        int orow = orow_base + r;
        if (orow < n) {
            float di = dinv[orow];
#pragma unroll
            for (int nt = 0; nt < NT; ++nt) {
                int col = nt * 16 + (lane & 15);
                if (col < NCOLS)
                    H[(long long)orow * NCOLS + col] =
                        (unsigned char)fp8_enc(acc[nt][r] * di);
            }
        }
    }
}

// Layer-1 aggregate (F=64 fp8): one wave per node; 8 edge-groups x 8 lanes;
// each lane loads uint2 = 8 fp8 feats. One gather instr covers 8 edges.
__global__ void __launch_bounds__(256)
k_gather_relu(const int* __restrict__ rowst, const int* __restrict__ csr,
              const unsigned char* __restrict__ h1s, const float* __restrict__ dinv,
              const float* __restrict__ b, unsigned short* __restrict__ out, int n) {
    long long gid = (long long)blockIdx.x * blockDim.x + threadIdx.x;
    int node = (int)(gid >> 6);
    int lane = (int)(gid & 63);
    if (node >= n) return;
    int eg = lane >> 3;         // edge group 0..7
    int fe = lane & 7;          // uint2 index within row (features 8fe..8fe+7)
    int jb = rowst[node], je = rowst[node + 1];

    float a0[8], a1[8];
#pragma unroll
    for (int k = 0; k < 8; ++k) { a0[k] = 0.f; a1[k] = 0.f; }

    int j = jb + eg;
    for (; j + 8 < je; j += 16) {
        int s0 = csr[j];
        int s1 = csr[j + 8];
        uint2 u0 = ((const uint2*)(h1s + (long long)s0 * 64))[fe];
        uint2 u1 = ((const uint2*)(h1s + (long long)s1 * 64))[fe];
        acc8_fp8(a0, u0);
        acc8_fp8(a1, u1);
    }
    if (j < je) {
        int s0 = csr[j];
        uint2 u0 = ((const uint2*)(h1s + (long long)s0 * 64))[fe];
        acc8_fp8(a0, u0);
    }
#pragma unroll
    for (int k = 0; k < 8; ++k) a0[k] += a1[k];

    // sum the 8 edge-groups (lanes l, l^8, l^16, ..., l^56)
#pragma unroll
    for (int k = 0; k < 8; ++k) {
        a0[k] += __shfl_xor(a0[k], 8);
        a0[k] += __shfl_xor(a0[k], 16);
        a0[k] += __shfl_xor(a0[k], 32);
    }

    if (eg == 0) {
        uint2 self = ((const uint2*)(h1s + (long long)node * 64))[fe];
        acc8_fp8(a0, self);
        float di = dinv[node];
        unsigned short r[8];
#pragma unroll
        for (int k = 0; k < 8; ++k) {
            float v = fmaxf(a0[k] * di + b[8 * fe + k], 0.0f);
            r[k] = (unsigned short)f2bf(v);
        }
        uint4 pk;
        pk.x = (unsigned)r[0] | ((unsigned)r[1] << 16);
        pk.y = (unsigned)r[2] | ((unsigned)r[3] << 16);
        pk.z = (unsigned)r[4] | ((unsigned)r[5] << 16);
        pk.w = (unsigned)r[6] | ((unsigned)r[7] << 16);
        ((uint4*)(out + (long long)node * 64))[fe] = pk;
    }
}

// Layer-2 aggregate + bias + log_softmax (F=40 fp8 in, fp32 out).
// 8 edge-groups x 8 lanes; row = 5 uint2 (fe<5 active).
__global__ void __launch_bounds__(256)
k_gather_lsm(const int* __restrict__ rowst, const int* __restrict__ csr,
             const unsigned char* __restrict__ h2s, const float* __restrict__ dinv,
             const float* __restrict__ b, float* __restrict__ out, int n) {
    long long gid = (long long)blockIdx.x * blockDim.x + threadIdx.x;
    int node = (int)(gid >> 6);
    int lane = (int)(gid & 63);
    if (node >= n) return;
    int eg = lane >> 3;
    int fe = lane & 7;
    bool act = (fe < 5);
    int jb = rowst[node], je = rowst[node + 1];

    float a0[8], a1[8];
#pragma unroll
    for (int k = 0; k < 8; ++k) { a0[k] = 0.f; a1[k] = 0.f; }

    int j = jb + eg;
    for (; j + 8 < je; j += 16) {
        int s0 = csr[j];
        int s1 = csr[j + 8];
        if (act) {
            uint2 u0 = ((const uint2*)(h2s + (long long)s0 * 40))[fe];
            uint2 u1 = ((const uint2*)(h2s + (long long)s1 * 40))[fe];
            acc8_fp8(a0, u0);
            acc8_fp8(a1, u1);
        }
    }
    if (j < je && act) {
        int s0 = csr[j];
        uint2 u0 = ((const uint2*)(h2s + (long long)s0 * 40))[fe];
        acc8_fp8(a0, u0);
    }
#pragma unroll
    for (int k = 0; k < 8; ++k) a0[k] += a1[k];

#pragma unroll
    for (int k = 0; k < 8; ++k) {
        a0[k] += __shfl_xor(a0[k], 8);
        a0[k] += __shfl_xor(a0[k], 16);
        a0[k] += __shfl_xor(a0[k], 32);
    }

    float va[8];
    float mloc = -INFINITY;
    if (act) {
        uint2 self = ((const uint2*)(h2s + (long long)node * 40))[fe];
        acc8_fp8(a0, self);
        float di = dinv[node];
#pragma unroll
        for (int k = 0; k < 8; ++k) {
            va[k] = a0[k] * di + b[8 * fe + k];
            mloc = fmaxf(mloc, va[k]);
        }
    }
    // wave-wide max over all 40 features
    float m = mloc;
#pragma unroll
    for (int off = 32; off > 0; off >>= 1) m = fmaxf(m, __shfl_xor(m, off));
    // sum of exp: only eg==0 contributes (all groups hold identical va)
    float ex = 0.0f;
    if (act && eg == 0) {
#pragma unroll
        for (int k = 0; k < 8; ++k) ex += expf(va[k] - m);
    }
#pragma unroll
    for (int off = 32; off > 0; off >>= 1) ex += __shfl_xor(ex, off);
    float lse = logf(ex);
    if (act && eg == 0) {
        float4 r0 = make_float4(va[0] - m - lse, va[1] - m - lse,
                                va[2] - m - lse, va[3] - m - lse);
        float4 r1 = make_float4(va[4] - m - lse, va[5] - m - lse,
                                va[6] - m - lse, va[7] - m - lse);
        *(float4*)(out + (long long)node * 40 + 8 * fe)     = r0;
        *(float4*)(out + (long long)node * 40 + 8 * fe + 4) = r1;
    }
}

extern "C" void kernel_launch(void* const* d_in, const int* in_sizes, int n_in,
                              void* d_out, int out_size, void* d_ws, size_t ws_size,
                              hipStream_t stream) {
    const float* x  = (const float*)d_in[0];
    const void*  ei = d_in[1];
    const float* W1 = (const float*)d_in[2];
    const float* b1 = (const float*)d_in[3];
    const float* W2 = (const float*)d_in[4];
    const float* b2 = (const float*)d_in[5];
    float* out = (float*)d_out;

    const long long E = (long long)in_sizes[1] / 2;   // 3,200,000
    const int nblk  = (int)((E + EPB - 1) / EPB);     // 391
    const int nscan = NBUCK * nblk;                   // 76,636

    char* w = (char*)d_ws;
    auto alloc = [&](size_t bytes) -> void* {
        void* p = (void*)w;
        w += (bytes + 255) & ~(size_t)255;
        return p;
    };
    int*      flag    = (int*)     alloc(4);
    int*      partial = (int*)     alloc(256 * 4);
    int*      histM   = (int*)     alloc((size_t)nscan * 4);
    int*      rowst   = (int*)     alloc(((size_t)NN + 1) * 4);
    float*    dinv    = (float*)   alloc((size_t)NN * 4);
    short*    pB1     = (short*)   alloc((size_t)8 * 4 * 64 * 8 * 2);   // 32 KB
    short*    pB2     = (short*)   alloc((size_t)2 * 3 * 64 * 8 * 2);   // 6 KB
    int*      csr     = (int*)     alloc((size_t)E * 4);
    unsigned* ebuf    = (unsigned*)alloc((size_t)E * 4);   // >= NN*64 bytes (12.8MB > 6.4MB)
    unsigned short* agg1 = (unsigned short*)alloc((size_t)NN * 64 * 2);
    unsigned char* h1s = (unsigned char*)ebuf;   // ebuf dead before gemm1 writes h1s
    unsigned char* h2s = h1s;                    // h1s dead after k_gather_relu

    const int B = 256;
    auto cdiv = [](long long a, long long b) { return (int)((a + b - 1) / b); };
    const int NB2 = cdiv(nscan, 1024);   // 75

    // 0) dtype detection + weight packing
    k_detect<<<1, 256, 0, stream>>>((const unsigned int*)ei, flag);
    k_packB<256, 64, 8, 4><<<cdiv(8 * 4 * 64, B), B, 0, stream>>>(W1, pB1);
    k_packB<64, 40, 2, 3><<<cdiv(2 * 3 * 64, B), B, 0, stream>>>(W2, pB2);

    // 1) bucketed CSR build (+ dinv) — all hot atomics in LDS
    k_hist<<<nblk, B, 0, stream>>>(ei, flag, E, nblk, histM);
    k_scan_partial<<<NB2, 256, 0, stream>>>(histM, partial, nscan);
    k_scan_top<<<1, 64, 0, stream>>>(partial, NB2);
    k_scan_down<<<NB2, 256, 0, stream>>>(histM, partial, nscan);
    k_scatter_edges<<<nblk, B, 0, stream>>>(ei, flag, E, nblk, histM, ebuf);
    k_bucket_csr<<<NBUCK, 512, 0, stream>>>(ebuf, histM, nblk, E, rowst, dinv, csr);

    // 2) h1s = fp8( (x @ W1) * dinv[row] )   via bf16 MFMA
    k_mfma_gemm<256, 64, 8, 4, false><<<cdiv(NN, 64), B, 0, stream>>>(x, pB1, dinv, h1s, NN);

    // 3) layer-1 aggregate + bias + ReLU  (fp8 in -> bf16 out)
    k_gather_relu<<<cdiv((long long)NN * 64, B), B, 0, stream>>>(rowst, csr, h1s, dinv, b1, agg1, NN);

    // 4) h2s = fp8( (agg1 @ W2) * dinv[row] )  via bf16 MFMA, bf16 A
    k_mfma_gemm<64, 40, 2, 3, true><<<cdiv(NN, 64), B, 0, stream>>>(agg1, pB2, dinv, h2s, NN);

    // 5) layer-2 aggregate + bias + log_softmax -> d_out (fp32)
    k_gather_lsm<<<cdiv((long long)NN * 64, B), B, 0, stream>>>(rowst, csr, h2s, dinv, b2, out, NN);
}

// Round 9
// 240.764 us; speedup vs baseline: 8.1240x; 1.0968x over previous
//
#include <hip/hip_runtime.h>
#include <hip/hip_bf16.h>
#include <math.h>

static constexpr int NN    = 100000;            // N_NODES
static constexpr int BSH   = 9;                 // bucket covers 512 nodes
static constexpr int NBUCK = (NN + 511) >> 9;   // 196
static constexpr int EPB   = 8192;              // edges per block in hist/scatter

typedef __attribute__((ext_vector_type(8))) short short8;
typedef __attribute__((ext_vector_type(4))) float f32x4;
typedef __attribute__((ext_vector_type(2))) float f32x2;

// HW fp8 conversion (gfx950). The builtins' word-select args must be
// IMMEDIATE constants -> template parameter, literal at each call site.
#if defined(__has_builtin)
#  if __has_builtin(__builtin_amdgcn_cvt_pk_f32_fp8) && __has_builtin(__builtin_amdgcn_cvt_pk_fp8_f32)
#    define USE_HW_FP8 1
#  endif
#endif
#ifndef USE_HW_FP8
#  define USE_HW_FP8 0
#endif

__device__ __forceinline__ short f2bf(float f) {
    __hip_bfloat16 h = __float2bfloat16(f);
    return __builtin_bit_cast(short, h);
}

// ---- software fp8 e4m3 (fallback only) ----
__device__ __forceinline__ float fp8_dec_sw(unsigned b) {
    unsigned u = ((b & 0x80u) << 24) | ((b & 0x7Fu) << 20);
    return __builtin_bit_cast(float, u) * 0x1p120f;
}
__device__ __forceinline__ unsigned fp8_enc_sw(float f) {
    unsigned u = __builtin_bit_cast(unsigned, f * 0x1p-120f);
    unsigned s = (u >> 24) & 0x80u;
    unsigned mag = u & 0x7FFFFFFFu;
    unsigned t = mag + 0x7FFFFu + ((mag >> 20) & 1u);
    unsigned r = t >> 20;
    if (r > 0x7Eu) r = 0x7Eu;
    return s | r;
}

// decode 2 fp8 from 16-bit half HI of word u -> f32x2 (HI is compile-time)
template<bool HI>
__device__ __forceinline__ f32x2 dec2w(unsigned u) {
#if USE_HW_FP8
    return __builtin_amdgcn_cvt_pk_f32_fp8(u, HI);
#else
    unsigned w = HI ? (u >> 16) : u;
    f32x2 r;
    r.x = fp8_dec_sw(w & 0xFFu);
    r.y = fp8_dec_sw((w >> 8) & 0xFFu);
    return r;
#endif
}
// encode 2 f32 -> 2 fp8 in low 16 bits
__device__ __forceinline__ unsigned enc2(float a, float b) {
#if USE_HW_FP8
    return (unsigned)__builtin_amdgcn_cvt_pk_fp8_f32(a, b, 0, false);
#else
    return fp8_enc_sw(a) | (fp8_enc_sw(b) << 8);
#endif
}

// accumulate 8 fp8 (uint2) into f32x2 a[4] (pairs: feats 0-1,2-3,4-5,6-7)
__device__ __forceinline__ void acc8(f32x2* a, uint2 u) {
    a[0] += dec2w<false>(u.x);
    a[1] += dec2w<true>(u.x);
    a[2] += dec2w<false>(u.y);
    a[3] += dec2w<true>(u.y);
}

// ---- edge index load: dtype (int32 vs int64) decided by device-side flag ----
__device__ __forceinline__ long long ldidx(const void* __restrict__ p, long long i, int is64) {
    if (is64) return ((const long long* __restrict__)p)[i];
    return (long long)((const int* __restrict__)p)[i];
}

__global__ void k_detect(const unsigned int* __restrict__ e32, int* __restrict__ flag) {
    __shared__ int any_nz;
    if (threadIdx.x == 0) any_nz = 0;
    __syncthreads();
    unsigned int nz = 0;
    for (int w = 1 + 2 * (int)threadIdx.x; w < 4096; w += 512)
        nz |= e32[w];
    if (nz) atomicOr(&any_nz, 1);
    __syncthreads();
    if (threadIdx.x == 0) *flag = (any_nz == 0) ? 1 : 0;   // 1 => int64
}

// ---- bucketed CSR build ----
__global__ void __launch_bounds__(256)
k_hist(const void* __restrict__ eidx, const int* __restrict__ flag, long long E,
       int nblk, int* __restrict__ histM) {
    __shared__ int h[NBUCK];
    for (int i = threadIdx.x; i < NBUCK; i += 256) h[i] = 0;
    __syncthreads();
    int is64 = *flag;
    long long base = (long long)blockIdx.x * EPB;
    long long end  = base + EPB < E ? base + EPB : E;
    for (long long e = base + threadIdx.x; e < end; e += 256) {
        int d = (int)ldidx(eidx, E + e, is64);
        atomicAdd(&h[d >> BSH], 1);
    }
    __syncthreads();
    for (int b = threadIdx.x; b < NBUCK; b += 256)
        histM[(long long)b * nblk + blockIdx.x] = h[b];
}

__global__ void k_scan_partial(const int* __restrict__ src, int* __restrict__ partial, int n) {
    __shared__ int sd[256];
    int tid = threadIdx.x;
    int base = blockIdx.x * 1024 + tid * 4;
    int s = 0;
#pragma unroll
    for (int k = 0; k < 4; ++k) { int i = base + k; if (i < n) s += src[i]; }
    sd[tid] = s; __syncthreads();
    for (int off = 128; off > 0; off >>= 1) {
        if (tid < off) sd[tid] += sd[tid + off];
        __syncthreads();
    }
    if (tid == 0) partial[blockIdx.x] = sd[0];
}

__global__ void k_scan_top(int* __restrict__ partial, int nb) {
    if (threadIdx.x == 0) {
        int run = 0;
        for (int i = 0; i < nb; ++i) { int v = partial[i]; partial[i] = run; run += v; }
    }
}

__global__ void k_scan_down(int* __restrict__ arr, const int* __restrict__ partial, int n) {
    __shared__ int sd[256];
    int tid = threadIdx.x;
    int base = blockIdx.x * 1024 + tid * 4;
    int v[4]; int s = 0;
#pragma unroll
    for (int k = 0; k < 4; ++k) { int i = base + k; v[k] = (i < n) ? arr[i] : 0; s += v[k]; }
    sd[tid] = s; __syncthreads();
    for (int off = 1; off < 256; off <<= 1) {
        int add = (tid >= off) ? sd[tid - off] : 0;
        __syncthreads();
        sd[tid] += add;
        __syncthreads();
    }
    int run = partial[blockIdx.x] + sd[tid] - s;
#pragma unroll
    for (int k = 0; k < 4; ++k) {
        int i = base + k;
        if (i < n) arr[i] = run;
        run += v[k];
    }
}

__global__ void __launch_bounds__(256)
k_scatter_edges(const void* __restrict__ eidx, const int* __restrict__ flag, long long E,
                int nblk, const int* __restrict__ histM, unsigned* __restrict__ ebuf) {
    __shared__ int cur[NBUCK];
    for (int b = threadIdx.x; b < NBUCK; b += 256)
        cur[b] = histM[(long long)b * nblk + blockIdx.x];
    __syncthreads();
    int is64 = *flag;
    long long base = (long long)blockIdx.x * EPB;
    long long end  = base + EPB < E ? base + EPB : E;
    for (long long e = base + threadIdx.x; e < end; e += 256) {
        int s = (int)ldidx(eidx, e, is64);
        int d = (int)ldidx(eidx, E + e, is64);
        int pos = atomicAdd(&cur[d >> BSH], 1);
        ebuf[pos] = (unsigned)s | ((unsigned)(d & 511) << 17);
    }
}

__global__ void __launch_bounds__(512)
k_bucket_csr(const unsigned* __restrict__ ebuf, const int* __restrict__ histM, int nblk,
             long long E, int* __restrict__ rowst, float* __restrict__ dinv,
             int* __restrict__ csr) {
    __shared__ int cnt[512];
    __shared__ int scn[512];
    __shared__ int cursor[512];
    int b = blockIdx.x;
    int t = threadIdx.x;
    long long b0 = histM[(long long)b * nblk];
    long long b1 = (b == NBUCK - 1) ? E : histM[(long long)(b + 1) * nblk];
    cnt[t] = 0;
    __syncthreads();
    for (long long e = b0 + t; e < b1; e += 512) {
        unsigned ed = ebuf[e];
        atomicAdd(&cnt[ed >> 17], 1);
    }
    __syncthreads();
    scn[t] = cnt[t];
    __syncthreads();
    for (int off = 1; off < 512; off <<= 1) {
        int v = (t >= off) ? scn[t - off] : 0;
        __syncthreads();
        scn[t] += v;
        __syncthreads();
    }
    int start = (int)b0 + scn[t] - cnt[t];
    int gnode = (b << BSH) + t;
    if (gnode < NN) {
        rowst[gnode] = start;
        dinv[gnode]  = rsqrtf((float)(cnt[t] + 1));
    }
    cursor[t] = start;
    if (t == 0 && b == NBUCK - 1) rowst[NN] = (int)E;
    __syncthreads();
    for (long long e = b0 + t; e < b1; e += 512) {
        unsigned ed = ebuf[e];
        int pos = atomicAdd(&cursor[ed >> 17], 1);
        csr[pos] = (int)(ed & 0x1FFFFu);
    }
}

// ---- MFMA GEMM machinery ----
template<int K, int NCOLS, int KT, int NT>
__global__ void k_packB(const float* __restrict__ W, short* __restrict__ P) {
    int t = blockIdx.x * blockDim.x + threadIdx.x;
    if (t >= KT * NT * 64) return;
    int kt = t / (NT * 64);
    int nt = (t / 64) % NT;
    int l  = t & 63;
    int g  = l >> 4;
#pragma unroll
    for (int e = 0; e < 8; ++e) {
        int k   = kt * 32 + g * 8 + e;
        int col = nt * 16 + (l & 15);
        float v = (col < NCOLS) ? W[k * NCOLS + col] : 0.0f;
        P[t * 8 + e] = f2bf(v);
    }
}

// H[i,:] = fp8( (X[i,:K] @ W) * dinv[i] ), fp32 accumulate via bf16 MFMA.
template<int K, int NCOLS, int KT, int NT, bool ABF16>
__global__ void __launch_bounds__(256)
k_mfma_gemm(const void* __restrict__ Xv, const short* __restrict__ packedB,
            const float* __restrict__ dinv, unsigned char* __restrict__ H, int n) {
    __shared__ alignas(16) short sW[KT * NT * 512];
    short8* dst = (short8*)sW;
    const short8* src = (const short8*)packedB;
    constexpr int TOT8 = KT * NT * 64;
    for (int i = threadIdx.x; i < TOT8; i += 256) dst[i] = src[i];
    __syncthreads();

    int wave = threadIdx.x >> 6, lane = threadIdx.x & 63;
    int g = lane >> 4;
    int arow = blockIdx.x * 64 + wave * 16 + (lane & 15);

    f32x4 acc[NT];
#pragma unroll
    for (int nt = 0; nt < NT; ++nt) acc[nt] = (f32x4){0.f, 0.f, 0.f, 0.f};

#pragma unroll
    for (int kt = 0; kt < KT; ++kt) {
        short8 a;
        if (arow < n) {
            int k0 = kt * 32 + g * 8;
            if (ABF16) {
                const short* xr = (const short*)Xv + (long long)arow * K;
                a = *(const short8*)(xr + k0);
            } else {
                const float* xr = (const float*)Xv + (long long)arow * K;
                float4 u = *(const float4*)(xr + k0);
                float4 v = *(const float4*)(xr + k0 + 4);
                a[0] = f2bf(u.x); a[1] = f2bf(u.y); a[2] = f2bf(u.z); a[3] = f2bf(u.w);
                a[4] = f2bf(v.x); a[5] = f2bf(v.y); a[6] = f2bf(v.z); a[7] = f2bf(v.w);
            }
        } else {
            a = (short8){0, 0, 0, 0, 0, 0, 0, 0};
        }
#pragma unroll
        for (int nt = 0; nt < NT; ++nt) {
            short8 bfr = dst[(kt * NT + nt) * 64 + lane];
            acc[nt] = __builtin_amdgcn_mfma_f32_16x16x32_bf16(a, bfr, acc[nt], 0, 0, 0);
        }
    }

    // C/D layout (HW-verified): col = lane&15, row = (lane>>4)*4 + reg
    int c = lane & 15;
    int orow_base = blockIdx.x * 64 + wave * 16 + g * 4;
#pragma unroll
    for (int r = 0; r < 4; ++r) {
        int orow = orow_base + r;
        if (orow < n) {
            float di = dinv[orow];
            float v[NT];
#pragma unroll
            for (int nt = 0; nt < NT; ++nt) v[nt] = acc[nt][r] * di;
            unsigned char* hp = H + (long long)orow * NCOLS;
#pragma unroll
            for (int p = 0; p < NT; p += 2) {
                unsigned wrd = enc2(v[p], (p + 1 < NT) ? v[p + 1] : 0.0f);
                int col0 = p * 16 + c;
                if (col0 < NCOLS) hp[col0] = (unsigned char)(wrd & 0xFFu);
                if (p + 1 < NT) {
                    int col1 = col0 + 16;
                    if (col1 < NCOLS) hp[col1] = (unsigned char)((wrd >> 8) & 0xFFu);
                }
            }
        }
    }
}

// Layer-1 aggregate (F=64 fp8): 8 edge-groups x 8 lanes; lane loads uint2 = 8 feats.
__global__ void __launch_bounds__(256)
k_gather_relu(const int* __restrict__ rowst, const int* __restrict__ csr,
              const unsigned char* __restrict__ h1s, const float* __restrict__ dinv,
              const float* __restrict__ b, unsigned short* __restrict__ out, int n) {
    long long gid = (long long)blockIdx.x * blockDim.x + threadIdx.x;
    int node = (int)(gid >> 6);
    int lane = (int)(gid & 63);
    if (node >= n) return;
    int eg = lane >> 3;         // edge group 0..7
    int fe = lane & 7;          // uint2 index within row (features 8fe..8fe+7)
    int jb = rowst[node], je = rowst[node + 1];
    unsigned feoff = (unsigned)fe << 3;

    f32x2 a0[4], a1[4];
#pragma unroll
    for (int q = 0; q < 4; ++q) { a0[q] = (f32x2){0.f, 0.f}; a1[q] = (f32x2){0.f, 0.f}; }

    int j = jb + eg;
    for (; j + 8 < je; j += 16) {
        int s0 = csr[j];
        int s1 = csr[j + 8];
        uint2 u0 = *(const uint2*)(h1s + (((unsigned)s0 << 6) + feoff));
        uint2 u1 = *(const uint2*)(h1s + (((unsigned)s1 << 6) + feoff));
        acc8(a0, u0);
        acc8(a1, u1);
    }
    if (j < je) {
        int s0 = csr[j];
        uint2 u0 = *(const uint2*)(h1s + (((unsigned)s0 << 6) + feoff));
        acc8(a0, u0);
    }
#pragma unroll
    for (int q = 0; q < 4; ++q) a0[q] += a1[q];

    // sum the 8 edge-groups (lanes l, l^8, l^16, ..., l^56)
#pragma unroll
    for (int q = 0; q < 4; ++q) {
        a0[q].x += __shfl_xor(a0[q].x, 8);
        a0[q].y += __shfl_xor(a0[q].y, 8);
        a0[q].x += __shfl_xor(a0[q].x, 16);
        a0[q].y += __shfl_xor(a0[q].y, 16);
        a0[q].x += __shfl_xor(a0[q].x, 32);
        a0[q].y += __shfl_xor(a0[q].y, 32);
    }

    if (eg == 0) {
        uint2 self = *(const uint2*)(h1s + (((unsigned)node << 6) + feoff));
        acc8(a0, self);
        float di = dinv[node];
        unsigned short r[8];
#pragma unroll
        for (int q = 0; q < 4; ++q) {
            float v0 = fmaxf(a0[q].x * di + b[8 * fe + 2 * q],     0.0f);
            float v1 = fmaxf(a0[q].y * di + b[8 * fe + 2 * q + 1], 0.0f);
            r[2 * q]     = (unsigned short)f2bf(v0);
            r[2 * q + 1] = (unsigned short)f2bf(v1);
        }
        uint4 pk;
        pk.x = (unsigned)r[0] | ((unsigned)r[1] << 16);
        pk.y = (unsigned)r[2] | ((unsigned)r[3] << 16);
        pk.z = (unsigned)r[4] | ((unsigned)r[5] << 16);
        pk.w = (unsigned)r[6] | ((unsigned)r[7] << 16);
        ((uint4*)(out + (long long)node * 64))[fe] = pk;
    }
}

// Layer-2 aggregate + bias + log_softmax (F=40 fp8 in, fp32 out).
__global__ void __launch_bounds__(256)
k_gather_lsm(const int* __restrict__ rowst, const int* __restrict__ csr,
             const unsigned char* __restrict__ h2s, const float* __restrict__ dinv,
             const float* __restrict__ b, float* __restrict__ out, int n) {
    long long gid = (long long)blockIdx.x * blockDim.x + threadIdx.x;
    int node = (int)(gid >> 6);
    int lane = (int)(gid & 63);
    if (node >= n) return;
    int eg = lane >> 3;
    int fe = lane & 7;
    bool act = (fe < 5);
    int jb = rowst[node], je = rowst[node + 1];
    unsigned feoff = (unsigned)fe << 3;

    f32x2 a0[4], a1[4];
#pragma unroll
    for (int q = 0; q < 4; ++q) { a0[q] = (f32x2){0.f, 0.f}; a1[q] = (f32x2){0.f, 0.f}; }

    int j = jb + eg;
    for (; j + 8 < je; j += 16) {
        int s0 = csr[j];
        int s1 = csr[j + 8];
        if (act) {
            uint2 u0 = *(const uint2*)(h2s + ((unsigned)s0 * 40u + feoff));
            uint2 u1 = *(const uint2*)(h2s + ((unsigned)s1 * 40u + feoff));
            acc8(a0, u0);
            acc8(a1, u1);
        }
    }
    if (j < je && act) {
        int s0 = csr[j];
        uint2 u0 = *(const uint2*)(h2s + ((unsigned)s0 * 40u + feoff));
        acc8(a0, u0);
    }
#pragma unroll
    for (int q = 0; q < 4; ++q) a0[q] += a1[q];

#pragma unroll
    for (int q = 0; q < 4; ++q) {
        a0[q].x += __shfl_xor(a0[q].x, 8);
        a0[q].y += __shfl_xor(a0[q].y, 8);
        a0[q].x += __shfl_xor(a0[q].x, 16);
        a0[q].y += __shfl_xor(a0[q].y, 16);
        a0[q].x += __shfl_xor(a0[q].x, 32);
        a0[q].y += __shfl_xor(a0[q].y, 32);
    }

    float va[8];
    float mloc = -INFINITY;
    if (act) {
        uint2 self = *(const uint2*)(h2s + ((unsigned)node * 40u + feoff));
        acc8(a0, self);
        float di = dinv[node];
#pragma unroll
        for (int q = 0; q < 4; ++q) {
            va[2 * q]     = a0[q].x * di + b[8 * fe + 2 * q];
            va[2 * q + 1] = a0[q].y * di + b[8 * fe + 2 * q + 1];
            mloc = fmaxf(mloc, fmaxf(va[2 * q], va[2 * q + 1]));
        }
    }
    float m = mloc;
#pragma unroll
    for (int off = 32; off > 0; off >>= 1) m = fmaxf(m, __shfl_xor(m, off));
    float ex = 0.0f;
    if (act && eg == 0) {
#pragma unroll
        for (int k = 0; k < 8; ++k) ex += expf(va[k] - m);
    }
#pragma unroll
    for (int off = 32; off > 0; off >>= 1) ex += __shfl_xor(ex, off);
    float lse = logf(ex);
    if (act && eg == 0) {
        float4 r0 = make_float4(va[0] - m - lse, va[1] - m - lse,
                                va[2] - m - lse, va[3] - m - lse);
        float4 r1 = make_float4(va[4] - m - lse, va[5] - m - lse,
                                va[6] - m - lse, va[7] - m - lse);
        *(float4*)(out + (long long)node * 40 + 8 * fe)     = r0;
        *(float4*)(out + (long long)node * 40 + 8 * fe + 4) = r1;
    }
}

extern "C" void kernel_launch(void* const* d_in, const int* in_sizes, int n_in,
                              void* d_out, int out_size, void* d_ws, size_t ws_size,
                              hipStream_t stream) {
    const float* x  = (const float*)d_in[0];
    const void*  ei = d_in[1];
    const float* W1 = (const float*)d_in[2];
    const float* b1 = (const float*)d_in[3];
    const float* W2 = (const float*)d_in[4];
    const float* b2 = (const float*)d_in[5];
    float* out = (float*)d_out;

    const long long E = (long long)in_sizes[1] / 2;   // 3,200,000
    const int nblk  = (int)((E + EPB - 1) / EPB);     // 391
    const int nscan = NBUCK * nblk;                   // 76,636

    char* w = (char*)d_ws;
    auto alloc = [&](size_t bytes) -> void* {
        void* p = (void*)w;
        w += (bytes + 255) & ~(size_t)255;
        return p;
    };
    int*      flag    = (int*)     alloc(4);
    int*      partial = (int*)     alloc(256 * 4);
    int*      histM   = (int*)     alloc((size_t)nscan * 4);
    int*      rowst   = (int*)     alloc(((size_t)NN + 1) * 4);
    float*    dinv    = (float*)   alloc((size_t)NN * 4);
    short*    pB1     = (short*)   alloc((size_t)8 * 4 * 64 * 8 * 2);   // 32 KB
    short*    pB2     = (short*)   alloc((size_t)2 * 3 * 64 * 8 * 2);   // 6 KB
    int*      csr     = (int*)     alloc((size_t)E * 4);
    unsigned* ebuf    = (unsigned*)alloc((size_t)E * 4);   // >= NN*64 B (12.8MB > 6.4MB)
    unsigned short* agg1 = (unsigned short*)alloc((size_t)NN * 64 * 2);
    unsigned char* h1s = (unsigned char*)ebuf;   // ebuf dead before gemm1 writes h1s
    unsigned char* h2s = h1s;                    // h1s dead after k_gather_relu

    const int B = 256;
    auto cdiv = [](long long a, long long b) { return (int)((a + b - 1) / b); };
    const int NB2 = cdiv(nscan, 1024);   // 75

    // 0) dtype detection + weight packing
    k_detect<<<1, 256, 0, stream>>>((const unsigned int*)ei, flag);
    k_packB<256, 64, 8, 4><<<cdiv(8 * 4 * 64, B), B, 0, stream>>>(W1, pB1);
    k_packB<64, 40, 2, 3><<<cdiv(2 * 3 * 64, B), B, 0, stream>>>(W2, pB2);

    // 1) bucketed CSR build (+ dinv) — all hot atomics in LDS
    k_hist<<<nblk, B, 0, stream>>>(ei, flag, E, nblk, histM);
    k_scan_partial<<<NB2, 256, 0, stream>>>(histM, partial, nscan);
    k_scan_top<<<1, 64, 0, stream>>>(partial, NB2);
    k_scan_down<<<NB2, 256, 0, stream>>>(histM, partial, nscan);
    k_scatter_edges<<<nblk, B, 0, stream>>>(ei, flag, E, nblk, histM, ebuf);
    k_bucket_csr<<<NBUCK, 512, 0, stream>>>(ebuf, histM, nblk, E, rowst, dinv, csr);

    // 2) h1s = fp8( (x @ W1) * dinv[row] )   via bf16 MFMA
    k_mfma_gemm<256, 64, 8, 4, false><<<cdiv(NN, 64), B, 0, stream>>>(x, pB1, dinv, h1s, NN);

    // 3) layer-1 aggregate + bias + ReLU  (fp8 in -> bf16 out)
    k_gather_relu<<<cdiv((long long)NN * 64, B), B, 0, stream>>>(rowst, csr, h1s, dinv, b1, agg1, NN);

    // 4) h2s = fp8( (agg1 @ W2) * dinv[row] )  via bf16 MFMA, bf16 A
    k_mfma_gemm<64, 40, 2, 3, true><<<cdiv(NN, 64), B, 0, stream>>>(agg1, pB2, dinv, h2s, NN);

    // 5) layer-2 aggregate + bias + log_softmax -> d_out (fp32)
    k_gather_lsm<<<cdiv((long long)NN * 64, B), B, 0, stream>>>(rowst, csr, h2s, dinv, b2, out, NN);
}

// Round 10
// 215.492 us; speedup vs baseline: 9.0767x; 1.1173x over previous
//
#include <hip/hip_runtime.h>
#include <hip/hip_bf16.h>
#include <math.h>

static constexpr int NN    = 100000;            // N_NODES
static constexpr int BSH   = 9;                 // bucket covers 512 nodes
static constexpr int NBUCK = (NN + 511) >> 9;   // 196
static constexpr int EPB   = 8192;              // edges per block in hist/scatter

typedef __attribute__((ext_vector_type(8))) short short8;
typedef __attribute__((ext_vector_type(4))) float f32x4;
typedef __attribute__((ext_vector_type(2))) float f32x2;

// HW fp8 conversion (gfx950). Word-select args must be IMMEDIATE constants.
#if defined(__has_builtin)
#  if __has_builtin(__builtin_amdgcn_cvt_pk_f32_fp8) && __has_builtin(__builtin_amdgcn_cvt_pk_fp8_f32)
#    define USE_HW_FP8 1
#  endif
#endif
#ifndef USE_HW_FP8
#  define USE_HW_FP8 0
#endif

__device__ __forceinline__ short f2bf(float f) {
    __hip_bfloat16 h = __float2bfloat16(f);
    return __builtin_bit_cast(short, h);
}

// ---- software fp8 e4m3 (fallback only) ----
__device__ __forceinline__ float fp8_dec_sw(unsigned b) {
    unsigned u = ((b & 0x80u) << 24) | ((b & 0x7Fu) << 20);
    return __builtin_bit_cast(float, u) * 0x1p120f;
}
__device__ __forceinline__ unsigned fp8_enc_sw(float f) {
    unsigned u = __builtin_bit_cast(unsigned, f * 0x1p-120f);
    unsigned s = (u >> 24) & 0x80u;
    unsigned mag = u & 0x7FFFFFFFu;
    unsigned t = mag + 0x7FFFFu + ((mag >> 20) & 1u);
    unsigned r = t >> 20;
    if (r > 0x7Eu) r = 0x7Eu;
    return s | r;
}

template<bool HI>
__device__ __forceinline__ f32x2 dec2w(unsigned u) {
#if USE_HW_FP8
    return __builtin_amdgcn_cvt_pk_f32_fp8(u, HI);
#else
    unsigned w = HI ? (u >> 16) : u;
    f32x2 r;
    r.x = fp8_dec_sw(w & 0xFFu);
    r.y = fp8_dec_sw((w >> 8) & 0xFFu);
    return r;
#endif
}
__device__ __forceinline__ unsigned enc2(float a, float b) {
#if USE_HW_FP8
    return (unsigned)__builtin_amdgcn_cvt_pk_fp8_f32(a, b, 0, false);
#else
    return fp8_enc_sw(a) | (fp8_enc_sw(b) << 8);
#endif
}

// accumulate 8 fp8 (uint2) into f32x2 a[4]
__device__ __forceinline__ void acc8(f32x2* a, uint2 u) {
    a[0] += dec2w<false>(u.x);
    a[1] += dec2w<true>(u.x);
    a[2] += dec2w<false>(u.y);
    a[3] += dec2w<true>(u.y);
}

// ---- edge index load ----
__device__ __forceinline__ long long ldidx(const void* __restrict__ p, long long i, int is64) {
    if (is64) return ((const long long* __restrict__)p)[i];
    return (long long)((const int* __restrict__)p)[i];
}

__global__ void k_detect(const unsigned int* __restrict__ e32, int* __restrict__ flag) {
    __shared__ int any_nz;
    if (threadIdx.x == 0) any_nz = 0;
    __syncthreads();
    unsigned int nz = 0;
    for (int w = 1 + 2 * (int)threadIdx.x; w < 4096; w += 512)
        nz |= e32[w];
    if (nz) atomicOr(&any_nz, 1);
    __syncthreads();
    if (threadIdx.x == 0) *flag = (any_nz == 0) ? 1 : 0;   // 1 => int64
}

// ---- bucketed CSR build ----
__global__ void __launch_bounds__(256)
k_hist(const void* __restrict__ eidx, const int* __restrict__ flag, long long E,
       int nblk, int* __restrict__ histM) {
    __shared__ int h[NBUCK];
    for (int i = threadIdx.x; i < NBUCK; i += 256) h[i] = 0;
    __syncthreads();
    int is64 = *flag;
    long long base = (long long)blockIdx.x * EPB;
    long long end  = base + EPB < E ? base + EPB : E;
    for (long long e = base + threadIdx.x; e < end; e += 256) {
        int d = (int)ldidx(eidx, E + e, is64);
        atomicAdd(&h[d >> BSH], 1);
    }
    __syncthreads();
    for (int b = threadIdx.x; b < NBUCK; b += 256)
        histM[(long long)b * nblk + blockIdx.x] = h[b];
}

__global__ void k_scan_partial(const int* __restrict__ src, int* __restrict__ partial, int n) {
    __shared__ int sd[256];
    int tid = threadIdx.x;
    int base = blockIdx.x * 1024 + tid * 4;
    int s = 0;
#pragma unroll
    for (int k = 0; k < 4; ++k) { int i = base + k; if (i < n) s += src[i]; }
    sd[tid] = s; __syncthreads();
    for (int off = 128; off > 0; off >>= 1) {
        if (tid < off) sd[tid] += sd[tid + off];
        __syncthreads();
    }
    if (tid == 0) partial[blockIdx.x] = sd[0];
}

__global__ void k_scan_top(int* __restrict__ partial, int nb) {
    if (threadIdx.x == 0) {
        int run = 0;
        for (int i = 0; i < nb; ++i) { int v = partial[i]; partial[i] = run; run += v; }
    }
}

__global__ void k_scan_down(int* __restrict__ arr, const int* __restrict__ partial, int n) {
    __shared__ int sd[256];
    int tid = threadIdx.x;
    int base = blockIdx.x * 1024 + tid * 4;
    int v[4]; int s = 0;
#pragma unroll
    for (int k = 0; k < 4; ++k) { int i = base + k; v[k] = (i < n) ? arr[i] : 0; s += v[k]; }
    sd[tid] = s; __syncthreads();
    for (int off = 1; off < 256; off <<= 1) {
        int add = (tid >= off) ? sd[tid - off] : 0;
        __syncthreads();
        sd[tid] += add;
        __syncthreads();
    }
    int run = partial[blockIdx.x] + sd[tid] - s;
#pragma unroll
    for (int k = 0; k < 4; ++k) {
        int i = base + k;
        if (i < n) arr[i] = run;
        run += v[k];
    }
}

__global__ void __launch_bounds__(256)
k_scatter_edges(const void* __restrict__ eidx, const int* __restrict__ flag, long long E,
                int nblk, const int* __restrict__ histM, unsigned* __restrict__ ebuf) {
    __shared__ int cur[NBUCK];
    for (int b = threadIdx.x; b < NBUCK; b += 256)
        cur[b] = histM[(long long)b * nblk + blockIdx.x];
    __syncthreads();
    int is64 = *flag;
    long long base = (long long)blockIdx.x * EPB;
    long long end  = base + EPB < E ? base + EPB : E;
    for (long long e = base + threadIdx.x; e < end; e += 256) {
        int s = (int)ldidx(eidx, e, is64);
        int d = (int)ldidx(eidx, E + e, is64);
        int pos = atomicAdd(&cur[d >> BSH], 1);
        ebuf[pos] = (unsigned)s | ((unsigned)(d & 511) << 17);
    }
}

__global__ void __launch_bounds__(512)
k_bucket_csr(const unsigned* __restrict__ ebuf, const int* __restrict__ histM, int nblk,
             long long E, int* __restrict__ rowst, float* __restrict__ dinv,
             int* __restrict__ csr) {
    __shared__ int cnt[512];
    __shared__ int scn[512];
    __shared__ int cursor[512];
    int b = blockIdx.x;
    int t = threadIdx.x;
    long long b0 = histM[(long long)b * nblk];
    long long b1 = (b == NBUCK - 1) ? E : histM[(long long)(b + 1) * nblk];
    cnt[t] = 0;
    __syncthreads();
    for (long long e = b0 + t; e < b1; e += 512) {
        unsigned ed = ebuf[e];
        atomicAdd(&cnt[ed >> 17], 1);
    }
    __syncthreads();
    scn[t] = cnt[t];
    __syncthreads();
    for (int off = 1; off < 512; off <<= 1) {
        int v = (t >= off) ? scn[t - off] : 0;
        __syncthreads();
        scn[t] += v;
        __syncthreads();
    }
    int start = (int)b0 + scn[t] - cnt[t];
    int gnode = (b << BSH) + t;
    if (gnode < NN) {
        rowst[gnode] = start;
        dinv[gnode]  = rsqrtf((float)(cnt[t] + 1));
    }
    cursor[t] = start;
    if (t == 0 && b == NBUCK - 1) rowst[NN] = (int)E;
    __syncthreads();
    for (long long e = b0 + t; e < b1; e += 512) {
        unsigned ed = ebuf[e];
        int pos = atomicAdd(&cursor[ed >> 17], 1);
        csr[pos] = (int)(ed & 0x1FFFFu);
    }
}

// ---- MFMA GEMM machinery ----
template<int K, int NCOLS, int KT, int NT>
__global__ void k_packB(const float* __restrict__ W, short* __restrict__ P) {
    int t = blockIdx.x * blockDim.x + threadIdx.x;
    if (t >= KT * NT * 64) return;
    int kt = t / (NT * 64);
    int nt = (t / 64) % NT;
    int l  = t & 63;
    int g  = l >> 4;
#pragma unroll
    for (int e = 0; e < 8; ++e) {
        int k   = kt * 32 + g * 8 + e;
        int col = nt * 16 + (l & 15);
        float v = (col < NCOLS) ? W[k * NCOLS + col] : 0.0f;
        P[t * 8 + e] = f2bf(v);
    }
}

// H[i,:] = fp8( (X[i,:K] @ W) * dinv[i] ), fp32 accumulate via bf16 MFMA.
template<int K, int NCOLS, int KT, int NT, bool ABF16>
__global__ void __launch_bounds__(256)
k_mfma_gemm(const void* __restrict__ Xv, const short* __restrict__ packedB,
            const float* __restrict__ dinv, unsigned char* __restrict__ H, int n) {
    __shared__ alignas(16) short sW[KT * NT * 512];
    short8* dst = (short8*)sW;
    const short8* src = (const short8*)packedB;
    constexpr int TOT8 = KT * NT * 64;
    for (int i = threadIdx.x; i < TOT8; i += 256) dst[i] = src[i];
    __syncthreads();

    int wave = threadIdx.x >> 6, lane = threadIdx.x & 63;
    int g = lane >> 4;
    int arow = blockIdx.x * 64 + wave * 16 + (lane & 15);

    f32x4 acc[NT];
#pragma unroll
    for (int nt = 0; nt < NT; ++nt) acc[nt] = (f32x4){0.f, 0.f, 0.f, 0.f};

#pragma unroll
    for (int kt = 0; kt < KT; ++kt) {
        short8 a;
        if (arow < n) {
            int k0 = kt * 32 + g * 8;
            if (ABF16) {
                const short* xr = (const short*)Xv + (long long)arow * K;
                a = *(const short8*)(xr + k0);
            } else {
                const float* xr = (const float*)Xv + (long long)arow * K;
                float4 u = *(const float4*)(xr + k0);
                float4 v = *(const float4*)(xr + k0 + 4);
                a[0] = f2bf(u.x); a[1] = f2bf(u.y); a[2] = f2bf(u.z); a[3] = f2bf(u.w);
                a[4] = f2bf(v.x); a[5] = f2bf(v.y); a[6] = f2bf(v.z); a[7] = f2bf(v.w);
            }
        } else {
            a = (short8){0, 0, 0, 0, 0, 0, 0, 0};
        }
#pragma unroll
        for (int nt = 0; nt < NT; ++nt) {
            short8 bfr = dst[(kt * NT + nt) * 64 + lane];
            acc[nt] = __builtin_amdgcn_mfma_f32_16x16x32_bf16(a, bfr, acc[nt], 0, 0, 0);
        }
    }

    int c = lane & 15;
    int orow_base = blockIdx.x * 64 + wave * 16 + g * 4;
#pragma unroll
    for (int r = 0; r < 4; ++r) {
        int orow = orow_base + r;
        if (orow < n) {
            float di = dinv[orow];
            float v[NT];
#pragma unroll
            for (int nt = 0; nt < NT; ++nt) v[nt] = acc[nt][r] * di;
            unsigned char* hp = H + (long long)orow * NCOLS;
#pragma unroll
            for (int p = 0; p < NT; p += 2) {
                unsigned wrd = enc2(v[p], (p + 1 < NT) ? v[p + 1] : 0.0f);
                int col0 = p * 16 + c;
                if (col0 < NCOLS) hp[col0] = (unsigned char)(wrd & 0xFFu);
                if (p + 1 < NT) {
                    int col1 = col0 + 16;
                    if (col1 < NCOLS) hp[col1] = (unsigned char)((wrd >> 8) & 0xFFu);
                }
            }
        }
    }
}

// Layer-1 aggregate (F=64 fp8): ONE 8-LANE GROUP PER NODE (8 nodes/wave).
// Lane fe covers feats 8fe..8fe+7 (uint2). No cross-lane shuffles at all.
__global__ void __launch_bounds__(256)
k_gather_relu(const int* __restrict__ rowst, const int* __restrict__ csr,
              const unsigned char* __restrict__ h1s, const float* __restrict__ dinv,
              const float* __restrict__ b, unsigned short* __restrict__ out, int n) {
    long long gid = (long long)blockIdx.x * blockDim.x + threadIdx.x;
    int node = (int)(gid >> 3);
    int fe   = (int)(gid & 7);
    if (node >= n) return;          // group-uniform (all 8 lanes share node)
    int jb = rowst[node], je = rowst[node + 1];
    unsigned feoff = (unsigned)fe << 3;

    f32x2 a0[4], a1[4];
#pragma unroll
    for (int q = 0; q < 4; ++q) { a0[q] = (f32x2){0.f, 0.f}; a1[q] = (f32x2){0.f, 0.f}; }

    int j = jb;
    for (; j + 1 < je; j += 2) {
        int s0 = csr[j];
        int s1 = csr[j + 1];
        uint2 u0 = *(const uint2*)(h1s + (((unsigned)s0 << 6) + feoff));
        uint2 u1 = *(const uint2*)(h1s + (((unsigned)s1 << 6) + feoff));
        acc8(a0, u0);
        acc8(a1, u1);
    }
    if (j < je) {
        int s0 = csr[j];
        uint2 u0 = *(const uint2*)(h1s + (((unsigned)s0 << 6) + feoff));
        acc8(a0, u0);
    }
#pragma unroll
    for (int q = 0; q < 4; ++q) a0[q] += a1[q];

    uint2 self = *(const uint2*)(h1s + (((unsigned)node << 6) + feoff));
    acc8(a0, self);
    float di = dinv[node];
    unsigned short r[8];
#pragma unroll
    for (int q = 0; q < 4; ++q) {
        float v0 = fmaxf(a0[q].x * di + b[8 * fe + 2 * q],     0.0f);
        float v1 = fmaxf(a0[q].y * di + b[8 * fe + 2 * q + 1], 0.0f);
        r[2 * q]     = (unsigned short)f2bf(v0);
        r[2 * q + 1] = (unsigned short)f2bf(v1);
    }
    uint4 pk;
    pk.x = (unsigned)r[0] | ((unsigned)r[1] << 16);
    pk.y = (unsigned)r[2] | ((unsigned)r[3] << 16);
    pk.z = (unsigned)r[4] | ((unsigned)r[5] << 16);
    pk.w = (unsigned)r[6] | ((unsigned)r[7] << 16);
    ((uint4*)(out + (long long)node * 64))[fe] = pk;
}

// Layer-2 aggregate + bias + log_softmax (F=40 fp8 in, fp32 out).
// ONE 8-LANE GROUP PER NODE; lanes fe<5 active; softmax via 3+3 group shuffles.
__global__ void __launch_bounds__(256)
k_gather_lsm(const int* __restrict__ rowst, const int* __restrict__ csr,
             const unsigned char* __restrict__ h2s, const float* __restrict__ dinv,
             const float* __restrict__ b, float* __restrict__ out, int n) {
    long long gid = (long long)blockIdx.x * blockDim.x + threadIdx.x;
    int node = (int)(gid >> 3);
    int fe   = (int)(gid & 7);
    if (node >= n) return;          // group-uniform
    bool act = (fe < 5);
    int jb = rowst[node], je = rowst[node + 1];
    unsigned feoff = (unsigned)fe << 3;

    f32x2 a0[4], a1[4];
#pragma unroll
    for (int q = 0; q < 4; ++q) { a0[q] = (f32x2){0.f, 0.f}; a1[q] = (f32x2){0.f, 0.f}; }

    int j = jb;
    for (; j + 1 < je; j += 2) {
        int s0 = csr[j];
        int s1 = csr[j + 1];
        if (act) {
            uint2 u0 = *(const uint2*)(h2s + ((unsigned)s0 * 40u + feoff));
            uint2 u1 = *(const uint2*)(h2s + ((unsigned)s1 * 40u + feoff));
            acc8(a0, u0);
            acc8(a1, u1);
        }
    }
    if (j < je && act) {
        int s0 = csr[j];
        uint2 u0 = *(const uint2*)(h2s + ((unsigned)s0 * 40u + feoff));
        acc8(a0, u0);
    }
#pragma unroll
    for (int q = 0; q < 4; ++q) a0[q] += a1[q];

    float va[8];
    float mloc = -INFINITY;
    if (act) {
        uint2 self = *(const uint2*)(h2s + ((unsigned)node * 40u + feoff));
        acc8(a0, self);
        float di = dinv[node];
#pragma unroll
        for (int q = 0; q < 4; ++q) {
            va[2 * q]     = a0[q].x * di + b[8 * fe + 2 * q];
            va[2 * q + 1] = a0[q].y * di + b[8 * fe + 2 * q + 1];
            mloc = fmaxf(mloc, fmaxf(va[2 * q], va[2 * q + 1]));
        }
    }
    // group max (xor within lane bits 0..2 stays inside the 8-lane group)
    float m = mloc;
    m = fmaxf(m, __shfl_xor(m, 1));
    m = fmaxf(m, __shfl_xor(m, 2));
    m = fmaxf(m, __shfl_xor(m, 4));
    // group sum of exp
    float ex = 0.0f;
    if (act) {
#pragma unroll
        for (int k = 0; k < 8; ++k) ex += __expf(va[k] - m);
    }
    ex += __shfl_xor(ex, 1);
    ex += __shfl_xor(ex, 2);
    ex += __shfl_xor(ex, 4);
    float lse = __logf(ex);
    if (act) {
        float4 r0 = make_float4(va[0] - m - lse, va[1] - m - lse,
                                va[2] - m - lse, va[3] - m - lse);
        float4 r1 = make_float4(va[4] - m - lse, va[5] - m - lse,
                                va[6] - m - lse, va[7] - m - lse);
        *(float4*)(out + (long long)node * 40 + 8 * fe)     = r0;
        *(float4*)(out + (long long)node * 40 + 8 * fe + 4) = r1;
    }
}

extern "C" void kernel_launch(void* const* d_in, const int* in_sizes, int n_in,
                              void* d_out, int out_size, void* d_ws, size_t ws_size,
                              hipStream_t stream) {
    const float* x  = (const float*)d_in[0];
    const void*  ei = d_in[1];
    const float* W1 = (const float*)d_in[2];
    const float* b1 = (const float*)d_in[3];
    const float* W2 = (const float*)d_in[4];
    const float* b2 = (const float*)d_in[5];
    float* out = (float*)d_out;

    const long long E = (long long)in_sizes[1] / 2;   // 3,200,000
    const int nblk  = (int)((E + EPB - 1) / EPB);     // 391
    const int nscan = NBUCK * nblk;                   // 76,636

    char* w = (char*)d_ws;
    auto alloc = [&](size_t bytes) -> void* {
        void* p = (void*)w;
        w += (bytes + 255) & ~(size_t)255;
        return p;
    };
    int*      flag    = (int*)     alloc(4);
    int*      partial = (int*)     alloc(256 * 4);
    int*      histM   = (int*)     alloc((size_t)nscan * 4);
    int*      rowst   = (int*)     alloc(((size_t)NN + 1) * 4);
    float*    dinv    = (float*)   alloc((size_t)NN * 4);
    short*    pB1     = (short*)   alloc((size_t)8 * 4 * 64 * 8 * 2);   // 32 KB
    short*    pB2     = (short*)   alloc((size_t)2 * 3 * 64 * 8 * 2);   // 6 KB
    int*      csr     = (int*)     alloc((size_t)E * 4);
    unsigned* ebuf    = (unsigned*)alloc((size_t)E * 4);   // >= NN*64 B
    unsigned short* agg1 = (unsigned short*)alloc((size_t)NN * 64 * 2);
    unsigned char* h1s = (unsigned char*)ebuf;   // ebuf dead before gemm1 writes h1s
    unsigned char* h2s = h1s;                    // h1s dead after k_gather_relu

    const int B = 256;
    auto cdiv = [](long long a, long long b) { return (int)((a + b - 1) / b); };
    const int NB2 = cdiv(nscan, 1024);   // 75

    // 0) dtype detection + weight packing
    k_detect<<<1, 256, 0, stream>>>((const unsigned int*)ei, flag);
    k_packB<256, 64, 8, 4><<<cdiv(8 * 4 * 64, B), B, 0, stream>>>(W1, pB1);
    k_packB<64, 40, 2, 3><<<cdiv(2 * 3 * 64, B), B, 0, stream>>>(W2, pB2);

    // 1) bucketed CSR build (+ dinv) — all hot atomics in LDS
    k_hist<<<nblk, B, 0, stream>>>(ei, flag, E, nblk, histM);
    k_scan_partial<<<NB2, 256, 0, stream>>>(histM, partial, nscan);
    k_scan_top<<<1, 64, 0, stream>>>(partial, NB2);
    k_scan_down<<<NB2, 256, 0, stream>>>(histM, partial, nscan);
    k_scatter_edges<<<nblk, B, 0, stream>>>(ei, flag, E, nblk, histM, ebuf);
    k_bucket_csr<<<NBUCK, 512, 0, stream>>>(ebuf, histM, nblk, E, rowst, dinv, csr);

    // 2) h1s = fp8( (x @ W1) * dinv[row] )   via bf16 MFMA
    k_mfma_gemm<256, 64, 8, 4, false><<<cdiv(NN, 64), B, 0, stream>>>(x, pB1, dinv, h1s, NN);

    // 3) layer-1 aggregate + bias + ReLU  (fp8 in -> bf16 out), 8 nodes/wave
    k_gather_relu<<<cdiv((long long)NN * 8, B), B, 0, stream>>>(rowst, csr, h1s, dinv, b1, agg1, NN);

    // 4) h2s = fp8( (agg1 @ W2) * dinv[row] )  via bf16 MFMA, bf16 A
    k_mfma_gemm<64, 40, 2, 3, true><<<cdiv(NN, 64), B, 0, stream>>>(agg1, pB2, dinv, h2s, NN);

    // 5) layer-2 aggregate + bias + log_softmax -> d_out (fp32), 8 nodes/wave
    k_gather_lsm<<<cdiv((long long)NN * 8, B), B, 0, stream>>>(rowst, csr, h2s, dinv, b2, out, NN);
}

// Round 11
// 214.097 us; speedup vs baseline: 9.1359x; 1.0065x over previous
//
#include <hip/hip_runtime.h>
#include <hip/hip_bf16.h>
#include <math.h>

static constexpr int NN    = 100000;            // N_NODES
static constexpr int BSH   = 9;                 // bucket covers 512 nodes
static constexpr int NBUCK = (NN + 511) >> 9;   // 196
static constexpr int EPB   = 8192;              // edges per block in scatter
static constexpr int CAP   = 24576;             // per-bucket region capacity (avg 16.3k)

typedef __attribute__((ext_vector_type(8))) short short8;
typedef __attribute__((ext_vector_type(4))) float f32x4;
typedef __attribute__((ext_vector_type(2))) float f32x2;

// HW fp8 conversion (gfx950). Word-select args must be IMMEDIATE constants.
#if defined(__has_builtin)
#  if __has_builtin(__builtin_amdgcn_cvt_pk_f32_fp8) && __has_builtin(__builtin_amdgcn_cvt_pk_fp8_f32)
#    define USE_HW_FP8 1
#  endif
#endif
#ifndef USE_HW_FP8
#  define USE_HW_FP8 0
#endif

__device__ __forceinline__ short f2bf(float f) {
    __hip_bfloat16 h = __float2bfloat16(f);
    return __builtin_bit_cast(short, h);
}

// ---- software fp8 e4m3 (fallback only) ----
__device__ __forceinline__ float fp8_dec_sw(unsigned b) {
    unsigned u = ((b & 0x80u) << 24) | ((b & 0x7Fu) << 20);
    return __builtin_bit_cast(float, u) * 0x1p120f;
}
__device__ __forceinline__ unsigned fp8_enc_sw(float f) {
    unsigned u = __builtin_bit_cast(unsigned, f * 0x1p-120f);
    unsigned s = (u >> 24) & 0x80u;
    unsigned mag = u & 0x7FFFFFFFu;
    unsigned t = mag + 0x7FFFFu + ((mag >> 20) & 1u);
    unsigned r = t >> 20;
    if (r > 0x7Eu) r = 0x7Eu;
    return s | r;
}

template<bool HI>
__device__ __forceinline__ f32x2 dec2w(unsigned u) {
#if USE_HW_FP8
    return __builtin_amdgcn_cvt_pk_f32_fp8(u, HI);
#else
    unsigned w = HI ? (u >> 16) : u;
    f32x2 r;
    r.x = fp8_dec_sw(w & 0xFFu);
    r.y = fp8_dec_sw((w >> 8) & 0xFFu);
    return r;
#endif
}
__device__ __forceinline__ unsigned enc2(float a, float b) {
#if USE_HW_FP8
    return (unsigned)__builtin_amdgcn_cvt_pk_fp8_f32(a, b, 0, false);
#else
    return fp8_enc_sw(a) | (fp8_enc_sw(b) << 8);
#endif
}

// accumulate 8 fp8 (uint2) into f32x2 a[4]
__device__ __forceinline__ void acc8(f32x2* a, uint2 u) {
    a[0] += dec2w<false>(u.x);
    a[1] += dec2w<true>(u.x);
    a[2] += dec2w<false>(u.y);
    a[3] += dec2w<true>(u.y);
}

// ---- edge index load ----
__device__ __forceinline__ long long ldidx(const void* __restrict__ p, long long i, int is64) {
    if (is64) return ((const long long* __restrict__)p)[i];
    return (long long)((const int* __restrict__)p)[i];
}

__global__ void k_detect(const unsigned int* __restrict__ e32, int* __restrict__ flag) {
    __shared__ int any_nz;
    if (threadIdx.x == 0) any_nz = 0;
    __syncthreads();
    unsigned int nz = 0;
    for (int w = 1 + 2 * (int)threadIdx.x; w < 4096; w += 512)
        nz |= e32[w];
    if (nz) atomicOr(&any_nz, 1);
    __syncthreads();
    if (threadIdx.x == 0) *flag = (any_nz == 0) ? 1 : 0;   // 1 => int64
}

// ---- one-pass bucketed edge scatter ----
// Per block: LDS-hist its slice -> reserve chunk per bucket via ONE global
// atomic per (block,bucket) -> scatter packed (src | ldst<<17) into
// ebuf[bucket*CAP + pos]. gcur must be zeroed beforehand; afterwards
// gcur[b] = bucket b's edge count.
__global__ void __launch_bounds__(256)
k_scatter_bucket(const void* __restrict__ eidx, const int* __restrict__ flag, long long E,
                 int* __restrict__ gcur, unsigned* __restrict__ ebuf) {
    __shared__ int h[NBUCK];   // hist -> block's base cursor per bucket
    for (int b = threadIdx.x; b < NBUCK; b += 256) h[b] = 0;
    __syncthreads();
    int is64 = *flag;
    long long base = (long long)blockIdx.x * EPB;
    long long end  = base + EPB < E ? base + EPB : E;
    // pass 1: histogram dst (slice is 64KB -> second read below hits L2)
    for (long long e = base + threadIdx.x; e < end; e += 256) {
        int d = (int)ldidx(eidx, E + e, is64);
        atomicAdd(&h[d >> BSH], 1);
    }
    __syncthreads();
    // reserve contiguous chunk in each bucket's region
    for (int b = threadIdx.x; b < NBUCK; b += 256)
        h[b] = atomicAdd(&gcur[b], h[b]);
    __syncthreads();
    // pass 2: scatter
    for (long long e = base + threadIdx.x; e < end; e += 256) {
        int s = (int)ldidx(eidx, e, is64);
        int d = (int)ldidx(eidx, E + e, is64);
        int bk = d >> BSH;
        int pos = atomicAdd(&h[bk], 1);
        ebuf[(long long)bk * CAP + pos] = (unsigned)s | ((unsigned)(d & 511) << 17);
    }
}

// exclusive scan of the 196 bucket counts -> global CSR bases; rowst[NN]=E
__global__ void k_bucket_starts(const int* __restrict__ gcnt, int* __restrict__ bstart,
                                int* __restrict__ rowst, int n) {
    if (threadIdx.x == 0) {
        int run = 0;
        for (int b = 0; b < NBUCK; ++b) { bstart[b] = run; run += gcnt[b]; }
        bstart[NBUCK] = run;
        rowst[n] = run;   // == E
    }
}

// per bucket (512 nodes): per-node counts + starts in LDS -> rowst, dinv, csr
__global__ void __launch_bounds__(512)
k_bucket_csr(const unsigned* __restrict__ ebuf, const int* __restrict__ gcnt,
             const int* __restrict__ bstart, int* __restrict__ rowst,
             float* __restrict__ dinv, int* __restrict__ csr) {
    __shared__ int cnt[512];
    __shared__ int scn[512];
    __shared__ int cursor[512];
    int b = blockIdx.x;
    int t = threadIdx.x;
    int cb = gcnt[b];
    long long rbase = (long long)b * CAP;
    int bs = bstart[b];
    cnt[t] = 0;
    __syncthreads();
    for (int i = t; i < cb; i += 512) {
        unsigned ed = ebuf[rbase + i];
        atomicAdd(&cnt[ed >> 17], 1);
    }
    __syncthreads();
    scn[t] = cnt[t];
    __syncthreads();
    for (int off = 1; off < 512; off <<= 1) {
        int v = (t >= off) ? scn[t - off] : 0;
        __syncthreads();
        scn[t] += v;
        __syncthreads();
    }
    int start = bs + scn[t] - cnt[t];
    int gnode = (b << BSH) + t;
    if (gnode < NN) {
        rowst[gnode] = start;
        dinv[gnode]  = rsqrtf((float)(cnt[t] + 1));
    }
    cursor[t] = start;
    __syncthreads();
    for (int i = t; i < cb; i += 512) {
        unsigned ed = ebuf[rbase + i];
        int pos = atomicAdd(&cursor[ed >> 17], 1);
        csr[pos] = (int)(ed & 0x1FFFFu);
    }
}

// ---- MFMA GEMM machinery ----
template<int K, int NCOLS, int KT, int NT>
__global__ void k_packB(const float* __restrict__ W, short* __restrict__ P) {
    int t = blockIdx.x * blockDim.x + threadIdx.x;
    if (t >= KT * NT * 64) return;
    int kt = t / (NT * 64);
    int nt = (t / 64) % NT;
    int l  = t & 63;
    int g  = l >> 4;
#pragma unroll
    for (int e = 0; e < 8; ++e) {
        int k   = kt * 32 + g * 8 + e;
        int col = nt * 16 + (l & 15);
        float v = (col < NCOLS) ? W[k * NCOLS + col] : 0.0f;
        P[t * 8 + e] = f2bf(v);
    }
}

// H[i,:] = fp8( (X[i,:K] @ W) * dinv[i] ), fp32 accumulate via bf16 MFMA.
template<int K, int NCOLS, int KT, int NT, bool ABF16>
__global__ void __launch_bounds__(256)
k_mfma_gemm(const void* __restrict__ Xv, const short* __restrict__ packedB,
            const float* __restrict__ dinv, unsigned char* __restrict__ H, int n) {
    __shared__ alignas(16) short sW[KT * NT * 512];
    short8* dst = (short8*)sW;
    const short8* src = (const short8*)packedB;
    constexpr int TOT8 = KT * NT * 64;
    for (int i = threadIdx.x; i < TOT8; i += 256) dst[i] = src[i];
    __syncthreads();

    int wave = threadIdx.x >> 6, lane = threadIdx.x & 63;
    int g = lane >> 4;
    int arow = blockIdx.x * 64 + wave * 16 + (lane & 15);

    f32x4 acc[NT];
#pragma unroll
    for (int nt = 0; nt < NT; ++nt) acc[nt] = (f32x4){0.f, 0.f, 0.f, 0.f};

#pragma unroll
    for (int kt = 0; kt < KT; ++kt) {
        short8 a;
        if (arow < n) {
            int k0 = kt * 32 + g * 8;
            if (ABF16) {
                const short* xr = (const short*)Xv + (long long)arow * K;
                a = *(const short8*)(xr + k0);
            } else {
                const float* xr = (const float*)Xv + (long long)arow * K;
                float4 u = *(const float4*)(xr + k0);
                float4 v = *(const float4*)(xr + k0 + 4);
                a[0] = f2bf(u.x); a[1] = f2bf(u.y); a[2] = f2bf(u.z); a[3] = f2bf(u.w);
                a[4] = f2bf(v.x); a[5] = f2bf(v.y); a[6] = f2bf(v.z); a[7] = f2bf(v.w);
            }
        } else {
            a = (short8){0, 0, 0, 0, 0, 0, 0, 0};
        }
#pragma unroll
        for (int nt = 0; nt < NT; ++nt) {
            short8 bfr = dst[(kt * NT + nt) * 64 + lane];
            acc[nt] = __builtin_amdgcn_mfma_f32_16x16x32_bf16(a, bfr, acc[nt], 0, 0, 0);
        }
    }

    int c = lane & 15;
    int orow_base = blockIdx.x * 64 + wave * 16 + g * 4;
#pragma unroll
    for (int r = 0; r < 4; ++r) {
        int orow = orow_base + r;
        if (orow < n) {
            float di = dinv[orow];
            float v[NT];
#pragma unroll
            for (int nt = 0; nt < NT; ++nt) v[nt] = acc[nt][r] * di;
            unsigned char* hp = H + (long long)orow * NCOLS;
#pragma unroll
            for (int p = 0; p < NT; p += 2) {
                unsigned wrd = enc2(v[p], (p + 1 < NT) ? v[p + 1] : 0.0f);
                int col0 = p * 16 + c;
                if (col0 < NCOLS) hp[col0] = (unsigned char)(wrd & 0xFFu);
                if (p + 1 < NT) {
                    int col1 = col0 + 16;
                    if (col1 < NCOLS) hp[col1] = (unsigned char)((wrd >> 8) & 0xFFu);
                }
            }
        }
    }
}

// Layer-1 aggregate (F=64 fp8): ONE 8-LANE GROUP PER NODE (8 nodes/wave).
__global__ void __launch_bounds__(256)
k_gather_relu(const int* __restrict__ rowst, const int* __restrict__ csr,
              const unsigned char* __restrict__ h1s, const float* __restrict__ dinv,
              const float* __restrict__ b, unsigned short* __restrict__ out, int n) {
    long long gid = (long long)blockIdx.x * blockDim.x + threadIdx.x;
    int node = (int)(gid >> 3);
    int fe   = (int)(gid & 7);
    if (node >= n) return;          // group-uniform
    int jb = rowst[node], je = rowst[node + 1];
    unsigned feoff = (unsigned)fe << 3;

    f32x2 a0[4], a1[4];
#pragma unroll
    for (int q = 0; q < 4; ++q) { a0[q] = (f32x2){0.f, 0.f}; a1[q] = (f32x2){0.f, 0.f}; }

    int j = jb;
    for (; j + 1 < je; j += 2) {
        int s0 = csr[j];
        int s1 = csr[j + 1];
        uint2 u0 = *(const uint2*)(h1s + (((unsigned)s0 << 6) + feoff));
        uint2 u1 = *(const uint2*)(h1s + (((unsigned)s1 << 6) + feoff));
        acc8(a0, u0);
        acc8(a1, u1);
    }
    if (j < je) {
        int s0 = csr[j];
        uint2 u0 = *(const uint2*)(h1s + (((unsigned)s0 << 6) + feoff));
        acc8(a0, u0);
    }
#pragma unroll
    for (int q = 0; q < 4; ++q) a0[q] += a1[q];

    uint2 self = *(const uint2*)(h1s + (((unsigned)node << 6) + feoff));
    acc8(a0, self);
    float di = dinv[node];
    unsigned short r[8];
#pragma unroll
    for (int q = 0; q < 4; ++q) {
        float v0 = fmaxf(a0[q].x * di + b[8 * fe + 2 * q],     0.0f);
        float v1 = fmaxf(a0[q].y * di + b[8 * fe + 2 * q + 1], 0.0f);
        r[2 * q]     = (unsigned short)f2bf(v0);
        r[2 * q + 1] = (unsigned short)f2bf(v1);
    }
    uint4 pk;
    pk.x = (unsigned)r[0] | ((unsigned)r[1] << 16);
    pk.y = (unsigned)r[2] | ((unsigned)r[3] << 16);
    pk.z = (unsigned)r[4] | ((unsigned)r[5] << 16);
    pk.w = (unsigned)r[6] | ((unsigned)r[7] << 16);
    ((uint4*)(out + (long long)node * 64))[fe] = pk;
}

// Layer-2 aggregate + bias + log_softmax (F=40 fp8 in, fp32 out).
__global__ void __launch_bounds__(256)
k_gather_lsm(const int* __restrict__ rowst, const int* __restrict__ csr,
             const unsigned char* __restrict__ h2s, const float* __restrict__ dinv,
             const float* __restrict__ b, float* __restrict__ out, int n) {
    long long gid = (long long)blockIdx.x * blockDim.x + threadIdx.x;
    int node = (int)(gid >> 3);
    int fe   = (int)(gid & 7);
    if (node >= n) return;          // group-uniform
    bool act = (fe < 5);
    int jb = rowst[node], je = rowst[node + 1];
    unsigned feoff = (unsigned)fe << 3;

    f32x2 a0[4], a1[4];
#pragma unroll
    for (int q = 0; q < 4; ++q) { a0[q] = (f32x2){0.f, 0.f}; a1[q] = (f32x2){0.f, 0.f}; }

    int j = jb;
    for (; j + 1 < je; j += 2) {
        int s0 = csr[j];
        int s1 = csr[j + 1];
        if (act) {
            uint2 u0 = *(const uint2*)(h2s + ((unsigned)s0 * 40u + feoff));
            uint2 u1 = *(const uint2*)(h2s + ((unsigned)s1 * 40u + feoff));
            acc8(a0, u0);
            acc8(a1, u1);
        }
    }
    if (j < je && act) {
        int s0 = csr[j];
        uint2 u0 = *(const uint2*)(h2s + ((unsigned)s0 * 40u + feoff));
        acc8(a0, u0);
    }
#pragma unroll
    for (int q = 0; q < 4; ++q) a0[q] += a1[q];

    float va[8];
    float mloc = -INFINITY;
    if (act) {
        uint2 self = *(const uint2*)(h2s + ((unsigned)node * 40u + feoff));
        acc8(a0, self);
        float di = dinv[node];
#pragma unroll
        for (int q = 0; q < 4; ++q) {
            va[2 * q]     = a0[q].x * di + b[8 * fe + 2 * q];
            va[2 * q + 1] = a0[q].y * di + b[8 * fe + 2 * q + 1];
            mloc = fmaxf(mloc, fmaxf(va[2 * q], va[2 * q + 1]));
        }
    }
    float m = mloc;
    m = fmaxf(m, __shfl_xor(m, 1));
    m = fmaxf(m, __shfl_xor(m, 2));
    m = fmaxf(m, __shfl_xor(m, 4));
    float ex = 0.0f;
    if (act) {
#pragma unroll
        for (int k = 0; k < 8; ++k) ex += __expf(va[k] - m);
    }
    ex += __shfl_xor(ex, 1);
    ex += __shfl_xor(ex, 2);
    ex += __shfl_xor(ex, 4);
    float lse = __logf(ex);
    if (act) {
        float4 r0 = make_float4(va[0] - m - lse, va[1] - m - lse,
                                va[2] - m - lse, va[3] - m - lse);
        float4 r1 = make_float4(va[4] - m - lse, va[5] - m - lse,
                                va[6] - m - lse, va[7] - m - lse);
        *(float4*)(out + (long long)node * 40 + 8 * fe)     = r0;
        *(float4*)(out + (long long)node * 40 + 8 * fe + 4) = r1;
    }
}

extern "C" void kernel_launch(void* const* d_in, const int* in_sizes, int n_in,
                              void* d_out, int out_size, void* d_ws, size_t ws_size,
                              hipStream_t stream) {
    const float* x  = (const float*)d_in[0];
    const void*  ei = d_in[1];
    const float* W1 = (const float*)d_in[2];
    const float* b1 = (const float*)d_in[3];
    const float* W2 = (const float*)d_in[4];
    const float* b2 = (const float*)d_in[5];
    float* out = (float*)d_out;

    const long long E = (long long)in_sizes[1] / 2;   // 3,200,000
    const int nblk = (int)((E + EPB - 1) / EPB);      // 391

    char* w = (char*)d_ws;
    auto alloc = [&](size_t bytes) -> void* {
        void* p = (void*)w;
        w += (bytes + 255) & ~(size_t)255;
        return p;
    };
    int*      flag    = (int*)     alloc(4);
    int*      gcur    = (int*)     alloc((size_t)NBUCK * 4);
    int*      bstart  = (int*)     alloc(((size_t)NBUCK + 1) * 4);
    int*      rowst   = (int*)     alloc(((size_t)NN + 1) * 4);
    float*    dinv    = (float*)   alloc((size_t)NN * 4);
    short*    pB1     = (short*)   alloc((size_t)8 * 4 * 64 * 8 * 2);   // 32 KB
    short*    pB2     = (short*)   alloc((size_t)2 * 3 * 64 * 8 * 2);   // 6 KB
    int*      csr     = (int*)     alloc((size_t)E * 4);
    unsigned* ebuf    = (unsigned*)alloc((size_t)NBUCK * CAP * 4);   // 19.3 MB
    unsigned short* agg1 = (unsigned short*)alloc((size_t)NN * 64 * 2);
    unsigned char* h1s = (unsigned char*)ebuf;   // ebuf dead before gemm1 writes h1s
    unsigned char* h2s = h1s;                    // h1s dead after k_gather_relu

    const int B = 256;
    auto cdiv = [](long long a, long long b) { return (int)((a + b - 1) / b); };

    // 0) dtype detection + weight packing
    k_detect<<<1, 256, 0, stream>>>((const unsigned int*)ei, flag);
    k_packB<256, 64, 8, 4><<<cdiv(8 * 4 * 64, B), B, 0, stream>>>(W1, pB1);
    k_packB<64, 40, 2, 3><<<cdiv(2 * 3 * 64, B), B, 0, stream>>>(W2, pB2);

    // 1) one-pass bucketed edge scatter + per-bucket CSR build (+ dinv)
    hipMemsetAsync(gcur, 0, (size_t)NBUCK * 4, stream);
    k_scatter_bucket<<<nblk, B, 0, stream>>>(ei, flag, E, gcur, ebuf);
    k_bucket_starts<<<1, 64, 0, stream>>>(gcur, bstart, rowst, NN);
    k_bucket_csr<<<NBUCK, 512, 0, stream>>>(ebuf, gcur, bstart, rowst, dinv, csr);

    // 2) h1s = fp8( (x @ W1) * dinv[row] )   via bf16 MFMA
    k_mfma_gemm<256, 64, 8, 4, false><<<cdiv(NN, 64), B, 0, stream>>>(x, pB1, dinv, h1s, NN);

    // 3) layer-1 aggregate + bias + ReLU  (fp8 in -> bf16 out), 8 nodes/wave
    k_gather_relu<<<cdiv((long long)NN * 8, B), B, 0, stream>>>(rowst, csr, h1s, dinv, b1, agg1, NN);

    // 4) h2s = fp8( (agg1 @ W2) * dinv[row] )  via bf16 MFMA, bf16 A
    k_mfma_gemm<64, 40, 2, 3, true><<<cdiv(NN, 64), B, 0, stream>>>(agg1, pB2, dinv, h2s, NN);

    // 5) layer-2 aggregate + bias + log_softmax -> d_out (fp32), 8 nodes/wave
    k_gather_lsm<<<cdiv((long long)NN * 8, B), B, 0, stream>>>(rowst, csr, h2s, dinv, b2, out, NN);
}